// Round 6
// baseline (316.365 us; speedup 1.0000x reference)
//
#include <hip/hip_runtime.h>
#include <hip/hip_bf16.h>
#include <stdint.h>

typedef unsigned short u16;
typedef __attribute__((ext_vector_type(8))) short s8v;
typedef __attribute__((ext_vector_type(4))) float f4v;

#define DEVI static __device__ __forceinline__

DEVI u16 f2bf(float x) {
  union { float f; unsigned u; } a; a.f = x;
  return (u16)((a.u + 0x7fffu + ((a.u >> 16) & 1u)) >> 16);  // RNE
}
DEVI float bf2f(u16 h) {
  union { float f; unsigned u; } a; a.u = ((unsigned)h) << 16; return a.f;
}
DEVI float wred_add(float s) {
#pragma unroll
  for (int o = 32; o; o >>= 1) s += __shfl_xor(s, o, 64);
  return s;
}
DEVI float wred_max(float s) {
#pragma unroll
  for (int o = 32; o; o >>= 1) s = fmaxf(s, __shfl_xor(s, o, 64));
  return s;
}
DEVI f4v mfma16(s8v a, s8v b, f4v c) {
  return __builtin_amdgcn_mfma_f32_16x16x32_bf16(a, b, c, 0, 0, 0);
}

// rho: within each 32-elem k-block, source elem j is STORED at position rho(j).
// Stored granule g (16B) = source elems {4g..4g+3, 16+4g..16+4g+3} == the MFMA
// k-slot set used since round 1 -> bitwise-identical MFMA inputs.
DEVI int rho(int j) { return ((j & 12) << 1) | (j & 3) | ((j >> 4) << 2); }

// async global->LDS, 16B per lane; LDS base wave-uniform, HW writes base+lane*16
DEVI void gload16(const u16* gp, u16* lp) {
  __builtin_amdgcn_global_load_lds(
      (const __attribute__((address_space(1))) uint32_t*)gp,
      (__attribute__((address_space(3))) uint32_t*)lp, 16, 0, 0);
}

// frag read: ONE ds_read_b128. LDS chunk = 16 rows x 64B; slot(r,lg) XOR-swizzled
// -> uniform 8 lanes/bank-quad, distinct addrs (verified r4/r5: BANK_CONFLICT == 0).
DEVI s8v ldfrag_sw(const u16* base, int r, int lg) {
  int off = ((r >> 4) << 9) + ((r & 15) << 5) + ((lg ^ ((r >> 1) & 3)) << 3);
  return *(const s8v*)(base + off);
}

// ---------------- elementwise split f32 -> bf16 hi/lo (rho-permuted cols) ----------------
__global__ __launch_bounds__(256) void split_k(const float* __restrict__ in,
                                               u16* __restrict__ h, u16* __restrict__ l, int n4) {
  int i = blockIdx.x * 256 + threadIdx.x;
  if (i >= n4) return;
  float4 v = ((const float4*)in)[i];
  ushort4 hv, lv;
  hv.x = f2bf(v.x); lv.x = f2bf(v.x - bf2f(hv.x));
  hv.y = f2bf(v.y); lv.y = f2bf(v.y - bf2f(hv.y));
  hv.z = f2bf(v.z); lv.z = f2bf(v.z - bf2f(hv.z));
  hv.w = f2bf(v.w); lv.w = f2bf(v.w - bf2f(hv.w));
  int t = i & 7, blk = i >> 3;
  int si = blk * 8 + ((t & 3) << 1) + (t >> 2);  // ushort4 slot of rho(4t)
  ((ushort4*)h)[si] = hv;
  ((ushort4*)l)[si] = lv;
}

// ---------------- transpose + split: f32 [z][R][C] -> bf16 [z][C][R], R rho'd ----------------
template<bool LO>
__global__ __launch_bounds__(256) void transpose_split_k(const float* __restrict__ in, long long zIn,
                                                         u16* __restrict__ outH, u16* __restrict__ outL,
                                                         long long zOut, int R, int C) {
  __shared__ float t[32][33];
  in += (long long)blockIdx.z * zIn;
  outH += (long long)blockIdx.z * zOut;
  if (LO) outL += (long long)blockIdx.z * zOut;
  const int cc = blockIdx.x * 32, rr = blockIdx.y * 32;
  const int tx = threadIdx.x, ty = threadIdx.y;  // (32,8)
#pragma unroll
  for (int i = 0; i < 4; ++i)
    t[ty * 4 + i][tx] = in[(long long)(rr + ty * 4 + i) * C + cc + tx];
  __syncthreads();
  const int rtx = rho(tx);
#pragma unroll
  for (int i = 0; i < 4; ++i) {
    float v = t[tx][ty * 4 + i];
    long long o = (long long)(cc + ty * 4 + i) * R + rr + rtx;
    u16 h = f2bf(v);
    outH[o] = h;
    if (LO) outL[o] = f2bf(v - bf2f(h));
  }
}

// ---------------- bf16-pair transpose: v slice of qkv (cols rho'd) -> vT [b][d][t] (t rho'd) ----------------
__global__ __launch_bounds__(256) void transpose_pair_k(const u16* __restrict__ inH, const u16* __restrict__ inL,
                                                        u16* __restrict__ oH, u16* __restrict__ oL) {
  __shared__ u16 th[32][34], tl[32][34];
  const int b = blockIdx.z;
  const int dd = blockIdx.x * 32;   // d in [0,1024)
  const int tt = blockIdx.y * 32;   // t in [0,512)
  const int tx = threadIdx.x, ty = threadIdx.y;  // (32,8)
  const int64_t ibase = ((int64_t)(b * 512 + tt)) * 3072 + 2048 + dd;
  const int rtx = rho(tx);
#pragma unroll
  for (int i = 0; i < 4; ++i) {
    int rr = ty * 4 + i;
    th[rr][tx] = inH[ibase + (int64_t)rr * 3072 + rtx];
    tl[rr][tx] = inL[ibase + (int64_t)rr * 3072 + rtx];
  }
  __syncthreads();
  const int64_t obase = ((int64_t)b * 1024 + dd) * 512 + tt;
#pragma unroll
  for (int i = 0; i < 4; ++i) {
    int rr = ty * 4 + i;
    oH[obase + (int64_t)rr * 512 + rtx] = th[tx][rr];
    oL[obase + (int64_t)rr * 512 + rtx] = tl[tx][rr];
  }
}

// ---------------- concat q,k,v biases ----------------
__global__ __launch_bounds__(256) void catb_k(const float* __restrict__ a, const float* __restrict__ b,
                                              const float* __restrict__ c, float* __restrict__ o) {
  int i = blockIdx.x * 256 + threadIdx.x;
  if (i >= 3072) return;
  o[i] = i < 1024 ? a[i] : (i < 2048 ? b[i - 1024] : c[i - 2048]);
}

// ---------------- generic MFMA GEMM: reg-prefetch + counted-vmcnt pipeline ----------------
// C[M,N] = A[M,K] @ B^T[N,K] (+bias). SPLIT: hi+lo bf16, 3 MFMAs (drop lo*lo).
// EPI: 0=f32(+bias), 1=split hi/lo bf16(+bias), 2=relu->bf16(+bias)
// PN: write C columns rho-permuted (when C later feeds a GEMM k-dim)
struct GemmArgs {
  const u16* Ah; const u16* Al; int lda;
  const u16* Bh; const u16* Bl; int ldb;
  float* C; u16* Ch; u16* Cl; int ldc;
  const float* bias;
  int K;
  int Z2;  // 0 = unbatched
  int64_t aZ1, aZ2, bZ1, bZ2, cZ1, cZ2;
  const int* ofs;      // [5], non-null => per-row-tile expert select
  int64_t bStrE; int biasStrE;
};

template<int BM, int BN, bool SPLIT, int EPI, bool PN>
__global__ __launch_bounds__(256, 3) void gemm_k(GemmArgs g) {
  constexpr int ASZ = BM * 32, BSZ = BN * 32;
  constexpr int AN = SPLIT ? 2 * ASZ : ASZ;
  constexpr int BNT = SPLIT ? 2 * BSZ : BSZ;
  constexpr int NLOAD = (BM / 64 + BN / 64) * (SPLIT ? 2 : 1);  // loads/lane/stage
  __shared__ __align__(16) u16 sA[2][AN];
  __shared__ __align__(16) u16 sB[2][BNT];

  const int tid = threadIdx.x;
  const u16* Ah = g.Ah; const u16* Al = g.Al;
  const u16* Bh = g.Bh; const u16* Bl = g.Bl;
  int64_t cOff = 0;
  if (g.Z2 > 0) {
    int z1 = blockIdx.z / g.Z2, z2 = blockIdx.z % g.Z2;
    int64_t ao = (int64_t)z1 * g.aZ1 + (int64_t)z2 * g.aZ2;
    int64_t bo = (int64_t)z1 * g.bZ1 + (int64_t)z2 * g.bZ2;
    Ah += ao; Bh += bo;
    if (SPLIT) { Al += ao; Bl += bo; }
    cOff = (int64_t)z1 * g.cZ1 + (int64_t)z2 * g.cZ2;
  }
  const int row0 = blockIdx.x * BM;
  const int col0 = blockIdx.y * BN;
  const float* bias = g.bias;
  if (g.ofs) {
    if (row0 >= g.ofs[4]) return;
    int e = 0;
    while (e < 3 && row0 >= g.ofs[e + 1]) ++e;
    Bh += (int64_t)e * g.bStrE;
    if (bias) bias += (int64_t)e * g.biasStrE;
  }

  const int w = tid >> 6, lane = tid & 63;
  const int wr = w >> 1, wc = w & 1;
  const int lr = lane & 15, lg = lane >> 4;
  constexpr int FM = BM / 32, FN = BN / 32;

  // staging: lane L stores LDS slot L; fetches global granule (L&3)^((L>>3)&3)
  const int srow = lane >> 2;
  const int sG = (lane & 3) ^ ((lane >> 3) & 3);

  auto stage = [&](int b, int kt) {
#pragma unroll
    for (int c = 0; c < BM / 64; ++c) {
      int ch = c * 4 + w;
      int64_t go = (int64_t)(row0 + ch * 16 + srow) * g.lda + kt + sG * 8;
      gload16(Ah + go, &sA[b][ch * 512]);
      if (SPLIT) gload16(Al + go, &sA[b][ASZ + ch * 512]);
    }
#pragma unroll
    for (int c = 0; c < BN / 64; ++c) {
      int ch = c * 4 + w;
      int64_t go = (int64_t)(col0 + ch * 16 + srow) * g.ldb + kt + sG * 8;
      gload16(Bh + go, &sB[b][ch * 512]);
      if (SPLIT) gload16(Bl + go, &sB[b][BSZ + ch * 512]);
    }
  };

  f4v acc[FM][FN];
#pragma unroll
  for (int i = 0; i < FM; ++i)
#pragma unroll
    for (int j = 0; j < FN; ++j) acc[i][j] = f4v{0.f, 0.f, 0.f, 0.f};

  // two named fragment register sets (static indexing only — no runtime idx)
  s8v a0[FM], b0[FN], al0[SPLIT ? FM : 1], bl0[SPLIT ? FN : 1];
  s8v a1[FM], b1[FN], al1[SPLIT ? FM : 1], bl1[SPLIT ? FN : 1];

  auto rdfrags = [&](int buf, auto& af, auto& bf, auto& afl, auto& bfl) {
#pragma unroll
    for (int mi = 0; mi < FM; ++mi) {
      int r = wr * (BM / 2) + mi * 16 + lr;
      af[mi] = ldfrag_sw(&sA[buf][0], r, lg);
      if (SPLIT) afl[mi] = ldfrag_sw(&sA[buf][ASZ], r, lg);
    }
#pragma unroll
    for (int ni = 0; ni < FN; ++ni) {
      int r = wc * (BN / 2) + ni * 16 + lr;
      bf[ni] = ldfrag_sw(&sB[buf][0], r, lg);
      if (SPLIT) bfl[ni] = ldfrag_sw(&sB[buf][BSZ], r, lg);
    }
  };

  const int nt = g.K >> 5;

  // prologue: fill both LDS buffers, read frag set 0
  stage(0, 0);
  stage(1, 32);
  asm volatile("s_waitcnt vmcnt(%0)" :: "n"(NLOAD) : "memory");  // buf0 landed
  __builtin_amdgcn_sched_barrier(0);
  __builtin_amdgcn_s_barrier();
  rdfrags(0, a0, b0, al0, bl0);

  // body(t): MFMA on cur set; prefetch next set's ds_reads UNDER the MFMAs.
  auto body = [&](int t, auto& cA, auto& cB, auto& cAl, auto& cBl,
                  auto& nA, auto& nB, auto& nAl, auto& nBl) {
    // my reads of buf[t&1] retired; after barrier ALL waves' reads retired
    asm volatile("s_waitcnt lgkmcnt(0)" ::: "memory");
    __builtin_amdgcn_sched_barrier(0);
    __builtin_amdgcn_s_barrier();
    if (t + 2 < nt) stage(t & 1, (t + 2) << 5);  // overwrite just-freed buffer
    if (t + 1 < nt) {
      if (t + 2 < nt)
        asm volatile("s_waitcnt vmcnt(%0)" :: "n"(NLOAD) : "memory");  // stage(t+1) done
      else
        asm volatile("s_waitcnt vmcnt(0)" ::: "memory");
      __builtin_amdgcn_sched_barrier(0);
      __builtin_amdgcn_s_barrier();
      rdfrags((t + 1) & 1, nA, nB, nAl, nBl);  // issues overlap MFMA below
    }
    __builtin_amdgcn_s_setprio(1);
#pragma unroll
    for (int mi = 0; mi < FM; ++mi)
#pragma unroll
      for (int ni = 0; ni < FN; ++ni) {
        acc[mi][ni] = mfma16(cA[mi], cB[ni], acc[mi][ni]);
        if (SPLIT) {
          acc[mi][ni] = mfma16(cA[mi], cBl[ni], acc[mi][ni]);
          acc[mi][ni] = mfma16(cAl[mi], cB[ni], acc[mi][ni]);
        }
      }
    __builtin_amdgcn_s_setprio(0);
  };

  for (int t = 0; t < nt; t += 2) {
    body(t,     a0, b0, al0, bl0, a1, b1, al1, bl1);
    body(t + 1, a1, b1, al1, bl1, a0, b0, al0, bl0);
  }

  // epilogue (C/D frag: col=lane&15, row=(lane>>4)*4+j — HW-verified layout)
#pragma unroll
  for (int mi = 0; mi < FM; ++mi) {
    int rbase = row0 + wr * (BM / 2) + mi * 16 + lg * 4;
#pragma unroll
    for (int ni = 0; ni < FN; ++ni) {
      int c = col0 + wc * (BN / 2) + ni * 16 + lr;  // source column (bias index)
      int cs = c;
      if (PN) {  // stored position: rho within 32-block
        int jr = ((lr >> 2) << 3) | (lr & 3) | ((ni & 1) << 2);
        cs = (c & ~31) | jr;
      }
      float bv = bias ? bias[c] : 0.f;
#pragma unroll
      for (int j = 0; j < 4; ++j) {
        int r = rbase + j;
        float v = acc[mi][ni][j] + bv;
        if (EPI == 0) {
          g.C[cOff + (int64_t)r * g.ldc + cs] = v;
        } else if (EPI == 1) {
          u16 h = f2bf(v);
          int64_t o = cOff + (int64_t)r * g.ldc + cs;
          g.Ch[o] = h;
          g.Cl[o] = f2bf(v - bf2f(h));
        } else {
          v = v > 0.f ? v : 0.f;
          g.Ch[cOff + (int64_t)r * g.ldc + cs] = f2bf(v);
        }
      }
    }
  }
}

// ---------------- split-K reduce (2-way): y[s] = part0[r]+part1[r] + b2[e], scatter ----------------
__global__ __launch_bounds__(256) void reduce_k(const float* __restrict__ part, const int* __restrict__ rowsrc,
                                                const int* __restrict__ ofs, const float* __restrict__ b2,
                                                float* __restrict__ y) {
  int r = blockIdx.x;
  if (r >= ofs[4]) return;
  int s = rowsrc[r];
  if (s < 0) return;
  int e = 0;
  while (e < 3 && r >= ofs[e + 1]) ++e;
  int c = threadIdx.x;
  const int64_t RN = 2560ll * 1024;
  float4 v0 = ((const float4*)(part + 0 * RN + (int64_t)r * 1024))[c];
  float4 v1 = ((const float4*)(part + 1 * RN + (int64_t)r * 1024))[c];
  float4 bb = ((const float4*)(b2 + (int64_t)e * 1024))[c];
  float4 o;
  o.x = (v0.x + v1.x) + bb.x;
  o.y = (v0.y + v1.y) + bb.y;
  o.z = (v0.z + v1.z) + bb.z;
  o.w = (v0.w + v1.w) + bb.w;
  ((float4*)(y + (int64_t)s * 1024))[c] = o;
}

// ---------------- softmax over 512 cols (position-oblivious), probs hi/lo IN PLACE ----------------
__global__ __launch_bounds__(128) void softmax_k(float* __restrict__ scores) {
  __shared__ float sm[2];
  const int64_t row = blockIdx.x;
  float* p = scores + row * 512;
  const int tid = threadIdx.x, w = tid >> 6, lane = tid & 63;
  float4 v = ((const float4*)p)[tid];
  v.x *= 0.125f; v.y *= 0.125f; v.z *= 0.125f; v.w *= 0.125f;
  float m = wred_max(fmaxf(fmaxf(v.x, v.y), fmaxf(v.z, v.w)));
  if (lane == 0) sm[w] = m;
  __syncthreads();
  m = fmaxf(sm[0], sm[1]);
  float e0 = expf(v.x - m), e1 = expf(v.y - m), e2 = expf(v.z - m), e3 = expf(v.w - m);
  float s = wred_add(e0 + e1 + e2 + e3);
  __syncthreads();
  if (lane == 0) sm[w] = s;
  __syncthreads();
  float inv = 1.f / (sm[0] + sm[1]);
  e0 *= inv; e1 *= inv; e2 *= inv; e3 *= inv;
  u16* ph = (u16*)p;  // row's own 2KB: hi at [0,512), lo at [512,1024) bf16 elems
  ushort4 hv, lv;
  hv.x = f2bf(e0); lv.x = f2bf(e0 - bf2f(hv.x));
  hv.y = f2bf(e1); lv.y = f2bf(e1 - bf2f(hv.y));
  hv.z = f2bf(e2); lv.z = f2bf(e2 - bf2f(hv.z));
  hv.w = f2bf(e3); lv.w = f2bf(e3 - bf2f(hv.w));
  ((ushort4*)ph)[tid] = hv;
  ((ushort4*)(ph + 512))[tid] = lv;
}

// ---------------- residual + layernorm ----------------
__global__ __launch_bounds__(256) void ln_k(const float* __restrict__ a, const float* __restrict__ b,
                                            const float* __restrict__ gm, const float* __restrict__ bt,
                                            float* __restrict__ out) {
  __shared__ float sm[4];
  const int r = blockIdx.x, tid = threadIdx.x;
  const int w = tid >> 6, lane = tid & 63;
  float4 va = ((const float4*)(a + (int64_t)r * 1024))[tid];
  float4 vb = ((const float4*)(b + (int64_t)r * 1024))[tid];
  float x0 = va.x + vb.x, x1 = va.y + vb.y, x2 = va.z + vb.z, x3 = va.w + vb.w;
  float s = wred_add(x0 + x1 + x2 + x3);
  if (lane == 0) sm[w] = s;
  __syncthreads();
  float mu = (sm[0] + sm[1] + sm[2] + sm[3]) * (1.f / 1024.f);
  float d0 = x0 - mu, d1 = x1 - mu, d2 = x2 - mu, d3 = x3 - mu;
  float q = wred_add(d0 * d0 + d1 * d1 + d2 * d2 + d3 * d3);
  __syncthreads();
  if (lane == 0) sm[w] = q;
  __syncthreads();
  float var = (sm[0] + sm[1] + sm[2] + sm[3]) * (1.f / 1024.f);
  float rs = 1.f / sqrtf(var + 1e-5f);
  float4 g4 = ((const float4*)gm)[tid];
  float4 b4 = ((const float4*)bt)[tid];
  float4 o;
  o.x = d0 * rs * g4.x + b4.x;
  o.y = d1 * rs * g4.y + b4.y;
  o.z = d2 * rs * g4.z + b4.z;
  o.w = d3 * rs * g4.w + b4.w;
  ((float4*)(out + (int64_t)r * 1024))[tid] = o;
}

// ---------------- router ----------------
__global__ __launch_bounds__(256) void router_k(const float* __restrict__ x, const float* __restrict__ rw,
                                                const float* __restrict__ rb, int* __restrict__ eidx) {
  int t = blockIdx.x * 4 + (threadIdx.x >> 6);
  int lane = threadIdx.x & 63;
  const float* xr = x + (int64_t)t * 1024;
  float s = 0.f;
#pragma unroll
  for (int i = 0; i < 16; ++i) {
    int c = i * 64 + lane;
    s += xr[c] * rw[c];
  }
  s = wred_add(s);
  if (lane == 0) {
    float key = s + rb[0];
    int f = (int)floorf(key);
    eidx[t] = f & 3;  // two's-complement & 3 == floor-mod 4
  }
}

// ---------------- stable compaction ----------------
__global__ __launch_bounds__(256) void compact_k(const int* __restrict__ eidx,
                                                 int* __restrict__ rowsrc, int* __restrict__ ofs) {
  __shared__ unsigned long long sc[256];
  __shared__ int soff[5];
  const int tid = threadIdx.x;
  int myE[8];
  unsigned long long c = 0;
#pragma unroll
  for (int i = 0; i < 8; ++i) {
    int e = eidx[tid * 8 + i];
    myE[i] = e;
    c += 1ull << (e * 16);
  }
  sc[tid] = c;
  __syncthreads();
  for (int o = 1; o < 256; o <<= 1) {
    unsigned long long v = (tid >= o) ? sc[tid - o] : 0ull;
    __syncthreads();
    sc[tid] += v;
    __syncthreads();
  }
  unsigned long long incl = sc[tid], tot = sc[255];
  unsigned long long excl = incl - c;
  if (tid == 0) {
    int off = 0;
    for (int e = 0; e < 4; ++e) {
      soff[e] = off;
      int cnt = (int)((tot >> (e * 16)) & 0xffff);
      off += (cnt + 127) & ~127;
    }
    soff[4] = off;
    for (int e = 0; e < 5; ++e) ofs[e] = soff[e];
  }
  __syncthreads();
  for (int r = tid; r < 2560; r += 256) rowsrc[r] = -1;
  __threadfence_block();
  __syncthreads();
  int rank[4];
#pragma unroll
  for (int e = 0; e < 4; ++e) rank[e] = (int)((excl >> (e * 16)) & 0xffff);
#pragma unroll
  for (int i = 0; i < 8; ++i) {
    int e = myE[i];
    rowsrc[soff[e] + rank[e]] = tid * 8 + i;
    rank[e]++;
  }
}

// ---------------- gather x rows (f32 -> bf16, rho-permuted cols) ----------------
__global__ __launch_bounds__(256) void gather_k(const float* __restrict__ x, const int* __restrict__ rowsrc,
                                                const int* __restrict__ ofs, u16* __restrict__ xg) {
  int r = blockIdx.x;
  if (r >= ofs[4]) return;
  int s = rowsrc[r];
  int c = threadIdx.x;  // source quad index
  float4 v = (s >= 0) ? ((const float4*)(x + (int64_t)s * 1024))[c] : float4{0.f, 0.f, 0.f, 0.f};
  ushort4 o;
  o.x = f2bf(v.x); o.y = f2bf(v.y); o.z = f2bf(v.z); o.w = f2bf(v.w);
  int t = c & 7, blk = c >> 3;
  int si = blk * 8 + ((t & 3) << 1) + (t >> 2);
  ((ushort4*)(xg + (int64_t)r * 1024))[si] = o;
}

// ---------------- host ----------------
extern "C" void kernel_launch(void* const* d_in, const int* in_sizes, int n_in,
                              void* d_out, int out_size, void* d_ws, size_t ws_size,
                              hipStream_t stream) {
  const float* src = (const float*)d_in[0];
  const float* Wq  = (const float*)d_in[1];
  const float* bq  = (const float*)d_in[2];
  const float* Wk  = (const float*)d_in[3];
  const float* bk  = (const float*)d_in[4];
  const float* Wv  = (const float*)d_in[5];
  const float* bv  = (const float*)d_in[6];
  const float* Wo  = (const float*)d_in[7];
  const float* bo  = (const float*)d_in[8];
  const float* rw  = (const float*)d_in[9];
  const float* rb  = (const float*)d_in[10];
  const float* W1  = (const float*)d_in[11];
  const float* b1  = (const float*)d_in[12];
  const float* W2  = (const float*)d_in[13];
  const float* b2  = (const float*)d_in[14];
  const float* g1  = (const float*)d_in[15];
  const float* be1 = (const float*)d_in[16];
  const float* g2  = (const float*)d_in[17];
  const float* be2 = (const float*)d_in[18];
  float* out = (float*)d_out;

  char* base = (char*)d_ws;
  size_t off = 0;
  auto alloc = [&](size_t bytes) -> char* {
    char* p = base + off;
    off += (bytes + 255) & ~(size_t)255;
    return p;
  };
  const size_t MB = 1ull << 20;
  u16* srcH = (u16*)alloc(4 * MB);
  u16* srcL = (u16*)alloc(4 * MB);
  u16* WqkvTh = (u16*)alloc(6 * MB);
  u16* WqkvTl = (u16*)alloc(6 * MB);
  u16* WoTh = (u16*)alloc(2 * MB);
  u16* WoTl = (u16*)alloc(2 * MB);
  float* bqkv = (float*)alloc(16 * 1024);
  u16* qkvH = (u16*)alloc(12 * MB);
  u16* qkvL = (u16*)alloc(12 * MB);
  u16* hbuf = (u16*)qkvH;  // alias: 20MB over qkvH+qkvL (24MB), dead by FFN time
  u16* vTH = (u16*)alloc(4 * MB); u16* vTL = (u16*)alloc(4 * MB);
  float* scores = (float*)alloc(64 * MB);  // probs in place; later W1T/W2T
  u16* W1T = (u16*)scores;
  u16* W2T = (u16*)scores + 16ull * 1024 * 1024;
  u16* attnH = (u16*)alloc(4 * MB); u16* attnL = (u16*)alloc(4 * MB);
  u16* xg = (u16*)attnH;  // alias: 5MB over attnH+attnL (8MB), dead after Wo GEMM
  float* woOut = (float*)alloc(8 * MB);
  float* ybuf = (float*)woOut;  // alias: dead after ln1
  float* xbuf = (float*)alloc(8 * MB);
  float* partials = (float*)alloc(20 * MB);  // 2 x 2560 x 1024 f32
  int* eidx   = (int*)alloc(2048 * 4);
  int* rowsrc = (int*)alloc(2560 * 4);
  int* ofs    = (int*)alloc(32);
  (void)ws_size; (void)in_sizes; (void)n_in; (void)out_size;

  dim3 tb(32, 8);

  // Phase 0: splits / weight transposes (attention)
  split_k<<<2048, 256, 0, stream>>>(src, srcH, srcL, 2048 * 1024 / 4);
  transpose_split_k<true><<<dim3(32, 32, 1), tb, 0, stream>>>(Wq, 0, WqkvTh, WqkvTl, 0, 1024, 1024);
  transpose_split_k<true><<<dim3(32, 32, 1), tb, 0, stream>>>(Wk, 0, WqkvTh + 1024 * 1024, WqkvTl + 1024 * 1024, 0, 1024, 1024);
  transpose_split_k<true><<<dim3(32, 32, 1), tb, 0, stream>>>(Wv, 0, WqkvTh + 2 * 1024 * 1024, WqkvTl + 2 * 1024 * 1024, 0, 1024, 1024);
  transpose_split_k<true><<<dim3(32, 32, 1), tb, 0, stream>>>(Wo, 0, WoTh, WoTl, 0, 1024, 1024);
  catb_k<<<12, 256, 0, stream>>>(bq, bk, bv, bqkv);

  // Phase 1: fused QKV projection (bf16x3) -> qkv hi/lo [2048][3072], cols rho'd
  {
    GemmArgs g{};
    g.Ah = srcH; g.Al = srcL; g.lda = 1024;
    g.Bh = WqkvTh; g.Bl = WqkvTl; g.ldb = 1024;
    g.Ch = qkvH; g.Cl = qkvL; g.ldc = 3072;
    g.bias = bqkv; g.K = 1024; g.Z2 = 0;
    gemm_k<128, 64, true, 1, true><<<dim3(16, 48, 1), 256, 0, stream>>>(g);
  }
  // v slice -> vT [b][d][t] hi/lo (lossless re-layout, t rho'd)
  transpose_pair_k<<<dim3(32, 16, 4), tb, 0, stream>>>(qkvH, qkvL, vTH, vTL);

  // Phase 2: scores = q @ k^T (bf16x3), batched over (b,h), t-cols rho'd
  {
    GemmArgs g{};
    g.Ah = qkvH; g.Al = qkvL; g.lda = 3072;
    g.Bh = qkvH + 1024; g.Bl = qkvL + 1024; g.ldb = 3072;
    g.C = scores; g.ldc = 512;
    g.K = 64; g.Z2 = 16;
    g.aZ1 = 512ll * 3072; g.aZ2 = 64;
    g.bZ1 = 512ll * 3072; g.bZ2 = 64;
    g.cZ1 = 16ll * 512 * 512; g.cZ2 = 512ll * 512;
    gemm_k<128, 64, true, 0, true><<<dim3(4, 8, 64), 256, 0, stream>>>(g);
  }
  softmax_k<<<64 * 512, 128, 0, stream>>>(scores);
  // PV: attn = probs @ v (bf16x3) -> attn hi/lo, d-cols rho'd
  {
    GemmArgs g{};
    g.Ah = (const u16*)scores; g.Al = (const u16*)scores + 512; g.lda = 1024;
    g.Bh = vTH; g.Bl = vTL; g.ldb = 512;
    g.Ch = attnH; g.Cl = attnL; g.ldc = 1024;
    g.K = 512; g.Z2 = 16;
    g.aZ1 = 16ll * 512 * 1024; g.aZ2 = 512ll * 1024;
    g.bZ1 = 1024ll * 512;      g.bZ2 = 64ll * 512;
    g.cZ1 = 512ll * 1024;      g.cZ2 = 64;
    gemm_k<64, 64, true, 1, true><<<dim3(8, 1, 64), 256, 0, stream>>>(g);
  }
  // Wo projection (bf16x3) + bias -> plain f32 (feeds LN/residual)
  {
    GemmArgs g{};
    g.Ah = attnH; g.Al = attnL; g.lda = 1024;
    g.Bh = WoTh; g.Bl = WoTl; g.ldb = 1024;
    g.C = woOut; g.ldc = 1024;
    g.bias = bo; g.K = 1024; g.Z2 = 0;
    gemm_k<64, 64, true, 0, false><<<dim3(32, 16, 1), 256, 0, stream>>>(g);
  }
  ln_k<<<2048, 256, 0, stream>>>(src, woOut, g1, be1, xbuf);

  // Phase 3: routing
  router_k<<<512, 256, 0, stream>>>(xbuf, rw, rb, eidx);
  compact_k<<<1, 256, 0, stream>>>(eidx, rowsrc, ofs);
  gather_k<<<2560, 256, 0, stream>>>(xbuf, rowsrc, ofs, xg);

  // FFN weights -> bf16 transposed (into dead scores region), k-dims rho'd
  transpose_split_k<false><<<dim3(128, 32, 4), tb, 0, stream>>>(W1, 1024ll * 4096, W1T, nullptr, 4096ll * 1024, 1024, 4096);
  transpose_split_k<false><<<dim3(32, 128, 4), tb, 0, stream>>>(W2, 4096ll * 1024, W2T, nullptr, 1024ll * 4096, 4096, 1024);

  // FFN1: h = relu(xg @ W1[e] + b1[e]) -> bf16, cols rho'd
  {
    GemmArgs g{};
    g.Ah = xg; g.lda = 1024;
    g.Bh = W1T; g.ldb = 1024;
    g.Ch = hbuf; g.ldc = 4096;
    g.bias = b1; g.biasStrE = 4096;
    g.K = 1024; g.Z2 = 0;
    g.ofs = ofs; g.bStrE = 4096ll * 1024;
    gemm_k<128, 128, false, 2, true><<<dim3(20, 32, 1), 256, 0, stream>>>(g);
  }
  // FFN2 split-K x2: partial[c] = h[:, c*2048:(c+1)*2048] @ W2[e][c*2048:..., :]
  {
    GemmArgs g{};
    g.Ah = hbuf; g.lda = 4096;
    g.Bh = W2T; g.ldb = 4096;
    g.C = partials; g.ldc = 1024;
    g.bias = nullptr;
    g.K = 2048; g.Z2 = 2;
    g.aZ1 = 0; g.aZ2 = 2048;       // K-chunk offset within A row
    g.bZ1 = 0; g.bZ2 = 2048;       // K-chunk offset within B row
    g.cZ1 = 0; g.cZ2 = 2560ll * 1024;
    g.ofs = ofs; g.bStrE = 4096ll * 1024;
    gemm_k<128, 64, false, 0, false><<<dim3(20, 16, 2), 256, 0, stream>>>(g);
  }
  reduce_k<<<2560, 256, 0, stream>>>(partials, rowsrc, ofs, b2, ybuf);
  ln_k<<<2048, 256, 0, stream>>>(xbuf, ybuf, g2, be2, out);
}

// Round 7
// 310.148 us; speedup vs baseline: 1.0200x; 1.0200x over previous
//
#include <hip/hip_runtime.h>
#include <hip/hip_bf16.h>
#include <stdint.h>

typedef unsigned short u16;
typedef __attribute__((ext_vector_type(8))) short s8v;
typedef __attribute__((ext_vector_type(4))) float f4v;

#define DEVI static __device__ __forceinline__

DEVI u16 f2bf(float x) {
  union { float f; unsigned u; } a; a.f = x;
  return (u16)((a.u + 0x7fffu + ((a.u >> 16) & 1u)) >> 16);  // RNE
}
DEVI float bf2f(u16 h) {
  union { float f; unsigned u; } a; a.u = ((unsigned)h) << 16; return a.f;
}
DEVI float wred_add(float s) {
#pragma unroll
  for (int o = 32; o; o >>= 1) s += __shfl_xor(s, o, 64);
  return s;
}
DEVI float wred_max(float s) {
#pragma unroll
  for (int o = 32; o; o >>= 1) s = fmaxf(s, __shfl_xor(s, o, 64));
  return s;
}
DEVI f4v mfma16(s8v a, s8v b, f4v c) {
  return __builtin_amdgcn_mfma_f32_16x16x32_bf16(a, b, c, 0, 0, 0);
}

// rho: within each 32-elem k-block, source elem j is STORED at position rho(j).
// Stored granule g (16B) = source elems {4g..4g+3, 16+4g..16+4g+3} == the MFMA
// k-slot set used since round 1 -> bitwise-identical MFMA inputs.
// rho(4g+i) = rho(4g)+i  (4-consecutive stays contiguous).
DEVI int rho(int j) { return ((j & 12) << 1) | (j & 3) | ((j >> 4) << 2); }

// async global->LDS, 16B per lane; LDS base wave-uniform, HW writes base+lane*16
DEVI void gload16(const u16* gp, u16* lp) {
  __builtin_amdgcn_global_load_lds(
      (const __attribute__((address_space(1))) uint32_t*)gp,
      (__attribute__((address_space(3))) uint32_t*)lp, 16, 0, 0);
}

// frag read: ONE ds_read_b128. LDS chunk = 16 rows x 64B; slot(r,lg) XOR-swizzled
// -> uniform 8 lanes/bank-quad, distinct addrs (verified r4-r6: BANK_CONFLICT == 0).
DEVI s8v ldfrag_sw(const u16* base, int r, int lg) {
  int off = ((r >> 4) << 9) + ((r & 15) << 5) + ((lg ^ ((r >> 1) & 3)) << 3);
  return *(const s8v*)(base + off);
}

// ---------------- elementwise split f32 -> bf16 hi/lo (rho-permuted cols) ----------------
__global__ __launch_bounds__(256) void split_k(const float* __restrict__ in,
                                               u16* __restrict__ h, u16* __restrict__ l, int n4) {
  int i = blockIdx.x * 256 + threadIdx.x;
  if (i >= n4) return;
  float4 v = ((const float4*)in)[i];
  ushort4 hv, lv;
  hv.x = f2bf(v.x); lv.x = f2bf(v.x - bf2f(hv.x));
  hv.y = f2bf(v.y); lv.y = f2bf(v.y - bf2f(hv.y));
  hv.z = f2bf(v.z); lv.z = f2bf(v.z - bf2f(hv.z));
  hv.w = f2bf(v.w); lv.w = f2bf(v.w - bf2f(hv.w));
  int t = i & 7, blk = i >> 3;
  int si = blk * 8 + ((t & 3) << 1) + (t >> 2);  // ushort4 slot of rho(4t)
  ((ushort4*)h)[si] = hv;
  ((ushort4*)l)[si] = lv;
}

// ---------------- transpose + split: f32 [z][R][C] -> bf16 [z][C][R], R rho'd ----------------
// vectorized: 32x128 tile, float4 loads, ushort4 stores
template<bool LO>
__global__ __launch_bounds__(256) void transpose_split_k(const float* __restrict__ in, long long zIn,
                                                         u16* __restrict__ outH, u16* __restrict__ outL,
                                                         long long zOut, int R, int C) {
  __shared__ float t[32][132];
  in += (long long)blockIdx.z * zIn;
  outH += (long long)blockIdx.z * zOut;
  if (LO) outL += (long long)blockIdx.z * zOut;
  const int cc = blockIdx.x * 128, rr = blockIdx.y * 32;
  const int id = threadIdx.y * 32 + threadIdx.x;  // (32,8) -> 0..255
#pragma unroll
  for (int i = 0; i < 4; ++i) {
    int slot = i * 256 + id;                 // 0..1023
    int r = slot >> 5, c4 = slot & 31;
    float4 v = *(const float4*)&in[(long long)(rr + r) * C + cc + c4 * 4];
    *(float4*)&t[r][c4 * 4] = v;
  }
  __syncthreads();
#pragma unroll
  for (int i = 0; i < 4; ++i) {
    int slot = i * 256 + id;
    int j = slot >> 3, gs = slot & 7;        // j: source col-in-tile, gs: 4-row group
    int r0 = gs * 4;
    float v0 = t[r0 + 0][j], v1 = t[r0 + 1][j], v2 = t[r0 + 2][j], v3 = t[r0 + 3][j];
    // stored base for rho(4*gs): 8*(gs&3) + 4*(gs>>2); rho keeps +0..3 contiguous
    long long o = (long long)(cc + j) * R + rr + 8 * (gs & 3) + 4 * (gs >> 2);
    ushort4 hv;
    hv.x = f2bf(v0); hv.y = f2bf(v1); hv.z = f2bf(v2); hv.w = f2bf(v3);
    *(ushort4*)&outH[o] = hv;
    if (LO) {
      ushort4 lv;
      lv.x = f2bf(v0 - bf2f(hv.x)); lv.y = f2bf(v1 - bf2f(hv.y));
      lv.z = f2bf(v2 - bf2f(hv.z)); lv.w = f2bf(v3 - bf2f(hv.w));
      *(ushort4*)&outL[o] = lv;
    }
  }
}

// ---------------- bf16-pair transpose: v slice of qkv (cols rho'd) -> vT [b][d][t] (t rho'd) ----------------
__global__ __launch_bounds__(256) void transpose_pair_k(const u16* __restrict__ inH, const u16* __restrict__ inL,
                                                        u16* __restrict__ oH, u16* __restrict__ oL) {
  __shared__ u16 th[32][34], tl[32][34];
  const int b = blockIdx.z;
  const int dd = blockIdx.x * 32;   // d in [0,1024)
  const int tt = blockIdx.y * 32;   // t in [0,512)
  const int tx = threadIdx.x, ty = threadIdx.y;  // (32,8)
  const int64_t ibase = ((int64_t)(b * 512 + tt)) * 3072 + 2048 + dd;
  const int rtx = rho(tx);
#pragma unroll
  for (int i = 0; i < 4; ++i) {
    int rr = ty * 4 + i;
    th[rr][tx] = inH[ibase + (int64_t)rr * 3072 + rtx];
    tl[rr][tx] = inL[ibase + (int64_t)rr * 3072 + rtx];
  }
  __syncthreads();
  const int64_t obase = ((int64_t)b * 1024 + dd) * 512 + tt;
#pragma unroll
  for (int i = 0; i < 4; ++i) {
    int rr = ty * 4 + i;
    oH[obase + (int64_t)rr * 512 + rtx] = th[tx][rr];
    oL[obase + (int64_t)rr * 512 + rtx] = tl[tx][rr];
  }
}

// ---------------- concat q,k,v biases ----------------
__global__ __launch_bounds__(256) void catb_k(const float* __restrict__ a, const float* __restrict__ b,
                                              const float* __restrict__ c, float* __restrict__ o) {
  int i = blockIdx.x * 256 + threadIdx.x;
  if (i >= 3072) return;
  o[i] = i < 1024 ? a[i] : (i < 2048 ? b[i - 1024] : c[i - 2048]);
}

// ---------------- generic MFMA GEMM: reg-prefetch + counted-vmcnt pipeline ----------------
// C[M,N] = A[M,K] @ B^T[N,K] (+bias). SPLIT: hi+lo bf16, 3 MFMAs (drop lo*lo).
// EPI: 0=f32(+bias), 1=split hi/lo bf16(+bias), 2=relu->bf16(+bias)
// PN: write C columns rho-permuted (when C later feeds a GEMM k-dim)
struct GemmArgs {
  const u16* Ah; const u16* Al; int lda;
  const u16* Bh; const u16* Bl; int ldb;
  float* C; u16* Ch; u16* Cl; int ldc;
  const float* bias;
  int K;
  int Z2;  // 0 = unbatched
  int64_t aZ1, aZ2, bZ1, bZ2, cZ1, cZ2;
  const int* ofs;      // [5], non-null => per-row-tile expert select
  int64_t bStrE; int biasStrE;
};

template<int BM, int BN, bool SPLIT, int EPI, bool PN, int MINW>
__global__ __launch_bounds__(256, MINW) void gemm_k(GemmArgs g) {
  constexpr int ASZ = BM * 32, BSZ = BN * 32;
  constexpr int AN = SPLIT ? 2 * ASZ : ASZ;
  constexpr int BNT = SPLIT ? 2 * BSZ : BSZ;
  constexpr int nA = BM / 16, nB = BN / 16;
  constexpr int nAt = SPLIT ? 2 * nA : nA;
  constexpr int TOT = nAt + (SPLIT ? 2 * nB : nB);
  static_assert(TOT % 4 == 0, "chunk count must divide across 4 waves");
  constexpr int NLOAD = TOT / 4;  // gloads per lane per stage
  __shared__ __align__(16) u16 sA[2][AN];
  __shared__ __align__(16) u16 sB[2][BNT];

  const int tid = threadIdx.x;
  const u16* Ah = g.Ah; const u16* Al = g.Al;
  const u16* Bh = g.Bh; const u16* Bl = g.Bl;
  int64_t cOff = 0;
  if (g.Z2 > 0) {
    int z1 = blockIdx.z / g.Z2, z2 = blockIdx.z % g.Z2;
    int64_t ao = (int64_t)z1 * g.aZ1 + (int64_t)z2 * g.aZ2;
    int64_t bo = (int64_t)z1 * g.bZ1 + (int64_t)z2 * g.bZ2;
    Ah += ao; Bh += bo;
    if (SPLIT) { Al += ao; Bl += bo; }
    cOff = (int64_t)z1 * g.cZ1 + (int64_t)z2 * g.cZ2;
  }
  const int row0 = blockIdx.x * BM;
  const int col0 = blockIdx.y * BN;
  const float* bias = g.bias;
  if (g.ofs) {
    if (row0 >= g.ofs[4]) return;
    int e = 0;
    while (e < 3 && row0 >= g.ofs[e + 1]) ++e;
    Bh += (int64_t)e * g.bStrE;
    if (bias) bias += (int64_t)e * g.biasStrE;
  }

  const int w = tid >> 6, lane = tid & 63;
  const int wr = w >> 1, wc = w & 1;
  const int lr = lane & 15, lg = lane >> 4;
  constexpr int FM = BM / 32, FN = BN / 32;

  // staging: lane L stores LDS slot L; fetches global granule (L&3)^((L>>3)&3)
  const int srow = lane >> 2;
  const int sG = (lane & 3) ^ ((lane >> 3) & 3);

  auto stage = [&](int b, int kt) {
#pragma unroll
    for (int c = 0; c < NLOAD; ++c) {
      int s = c * 4 + w;  // wave-uniform slot id
      if (s < nA) {
        int64_t go = (int64_t)(row0 + s * 16 + srow) * g.lda + kt + sG * 8;
        gload16(Ah + go, &sA[b][s * 512]);
      } else if (SPLIT && s < 2 * nA) {
        int ch = s - nA;
        int64_t go = (int64_t)(row0 + ch * 16 + srow) * g.lda + kt + sG * 8;
        gload16(Al + go, &sA[b][ASZ + ch * 512]);
      } else if (s < nAt + nB) {
        int ch = s - nAt;
        int64_t go = (int64_t)(col0 + ch * 16 + srow) * g.ldb + kt + sG * 8;
        gload16(Bh + go, &sB[b][ch * 512]);
      } else {
        int ch = s - nAt - nB;
        int64_t go = (int64_t)(col0 + ch * 16 + srow) * g.ldb + kt + sG * 8;
        gload16(Bl + go, &sB[b][BSZ + ch * 512]);
      }
    }
  };

  f4v acc[FM][FN];
#pragma unroll
  for (int i = 0; i < FM; ++i)
#pragma unroll
    for (int j = 0; j < FN; ++j) acc[i][j] = f4v{0.f, 0.f, 0.f, 0.f};

  // two named fragment register sets (static indexing only)
  s8v a0[FM], b0[FN], al0[SPLIT ? FM : 1], bl0[SPLIT ? FN : 1];
  s8v a1[FM], b1[FN], al1[SPLIT ? FM : 1], bl1[SPLIT ? FN : 1];

  auto rdfrags = [&](int buf, auto& af, auto& bf, auto& afl, auto& bfl) {
#pragma unroll
    for (int mi = 0; mi < FM; ++mi) {
      int r = wr * (BM / 2) + mi * 16 + lr;
      af[mi] = ldfrag_sw(&sA[buf][0], r, lg);
      if (SPLIT) afl[mi] = ldfrag_sw(&sA[buf][ASZ], r, lg);
    }
#pragma unroll
    for (int ni = 0; ni < FN; ++ni) {
      int r = wc * (BN / 2) + ni * 16 + lr;
      bf[ni] = ldfrag_sw(&sB[buf][0], r, lg);
      if (SPLIT) bfl[ni] = ldfrag_sw(&sB[buf][BSZ], r, lg);
    }
  };

  const int nt = g.K >> 5;

  stage(0, 0);
  stage(1, 32);
  asm volatile("s_waitcnt vmcnt(%0)" :: "n"(NLOAD) : "memory");  // buf0 landed
  __builtin_amdgcn_sched_barrier(0);
  __builtin_amdgcn_s_barrier();
  rdfrags(0, a0, b0, al0, bl0);

  auto body = [&](int t, auto& cA, auto& cB, auto& cAl, auto& cBl,
                  auto& nA_, auto& nB_, auto& nAl_, auto& nBl_) {
    // my reads of buf[t&1] retired; after barrier ALL waves' reads retired
    asm volatile("s_waitcnt lgkmcnt(0)" ::: "memory");
    __builtin_amdgcn_sched_barrier(0);
    __builtin_amdgcn_s_barrier();
    if (t + 2 < nt) stage(t & 1, (t + 2) << 5);  // overwrite just-freed buffer
    if (t + 1 < nt) {
      if (t + 2 < nt)
        asm volatile("s_waitcnt vmcnt(%0)" :: "n"(NLOAD) : "memory");  // stage(t+1) done
      else
        asm volatile("s_waitcnt vmcnt(0)" ::: "memory");
      __builtin_amdgcn_sched_barrier(0);
      __builtin_amdgcn_s_barrier();
      rdfrags((t + 1) & 1, nA_, nB_, nAl_, nBl_);  // issue next-step ds_reads...
    }
    __builtin_amdgcn_sched_barrier(0);  // ...pinned BEFORE the MFMA cluster
    __builtin_amdgcn_s_setprio(1);
#pragma unroll
    for (int mi = 0; mi < FM; ++mi)
#pragma unroll
      for (int ni = 0; ni < FN; ++ni) {
        acc[mi][ni] = mfma16(cA[mi], cB[ni], acc[mi][ni]);
        if (SPLIT) {
          acc[mi][ni] = mfma16(cA[mi], cBl[ni], acc[mi][ni]);
          acc[mi][ni] = mfma16(cAl[mi], cB[ni], acc[mi][ni]);
        }
      }
    __builtin_amdgcn_s_setprio(0);
  };

  for (int t = 0; t < nt; t += 2) {
    body(t,     a0, b0, al0, bl0, a1, b1, al1, bl1);
    body(t + 1, a1, b1, al1, bl1, a0, b0, al0, bl0);
  }

  // epilogue (C/D frag: col=lane&15, row=(lane>>4)*4+j — HW-verified layout)
#pragma unroll
  for (int mi = 0; mi < FM; ++mi) {
    int rbase = row0 + wr * (BM / 2) + mi * 16 + lg * 4;
#pragma unroll
    for (int ni = 0; ni < FN; ++ni) {
      int c = col0 + wc * (BN / 2) + ni * 16 + lr;  // source column (bias index)
      int cs = PN ? ((c & ~31) | rho(c & 31)) : c;  // stored position
      float bv = bias ? bias[c] : 0.f;
#pragma unroll
      for (int j = 0; j < 4; ++j) {
        int r = rbase + j;
        float v = acc[mi][ni][j] + bv;
        if (EPI == 0) {
          g.C[cOff + (int64_t)r * g.ldc + cs] = v;
        } else if (EPI == 1) {
          u16 h = f2bf(v);
          int64_t o = cOff + (int64_t)r * g.ldc + cs;
          g.Ch[o] = h;
          g.Cl[o] = f2bf(v - bf2f(h));
        } else {
          v = v > 0.f ? v : 0.f;
          g.Ch[cOff + (int64_t)r * g.ldc + cs] = f2bf(v);
        }
      }
    }
  }
}

// ---------------- softmax over 512 cols (position-oblivious), probs hi/lo IN PLACE ----------------
__global__ __launch_bounds__(128) void softmax_k(float* __restrict__ scores) {
  __shared__ float sm[2];
  const int64_t row = blockIdx.x;
  float* p = scores + row * 512;
  const int tid = threadIdx.x, w = tid >> 6, lane = tid & 63;
  float4 v = ((const float4*)p)[tid];
  v.x *= 0.125f; v.y *= 0.125f; v.z *= 0.125f; v.w *= 0.125f;
  float m = wred_max(fmaxf(fmaxf(v.x, v.y), fmaxf(v.z, v.w)));
  if (lane == 0) sm[w] = m;
  __syncthreads();
  m = fmaxf(sm[0], sm[1]);
  float e0 = expf(v.x - m), e1 = expf(v.y - m), e2 = expf(v.z - m), e3 = expf(v.w - m);
  float s = wred_add(e0 + e1 + e2 + e3);
  __syncthreads();
  if (lane == 0) sm[w] = s;
  __syncthreads();
  float inv = 1.f / (sm[0] + sm[1]);
  e0 *= inv; e1 *= inv; e2 *= inv; e3 *= inv;
  u16* ph = (u16*)p;  // row's own 2KB: hi at [0,512), lo at [512,1024) bf16 elems
  ushort4 hv, lv;
  hv.x = f2bf(e0); lv.x = f2bf(e0 - bf2f(hv.x));
  hv.y = f2bf(e1); lv.y = f2bf(e1 - bf2f(hv.y));
  hv.z = f2bf(e2); lv.z = f2bf(e2 - bf2f(hv.z));
  hv.w = f2bf(e3); lv.w = f2bf(e3 - bf2f(hv.w));
  ((ushort4*)ph)[tid] = hv;
  ((ushort4*)(ph + 512))[tid] = lv;
}

// ---------------- residual + layernorm + fused router ----------------
__global__ __launch_bounds__(256) void ln_router_k(const float* __restrict__ a, const float* __restrict__ b,
                                                   const float* __restrict__ gm, const float* __restrict__ bt,
                                                   const float* __restrict__ rw, const float* __restrict__ rb,
                                                   float* __restrict__ out, int* __restrict__ eidx) {
  __shared__ float sm[4];
  const int r = blockIdx.x, tid = threadIdx.x;
  const int w = tid >> 6, lane = tid & 63;
  float4 va = ((const float4*)(a + (int64_t)r * 1024))[tid];
  float4 vb = ((const float4*)(b + (int64_t)r * 1024))[tid];
  float x0 = va.x + vb.x, x1 = va.y + vb.y, x2 = va.z + vb.z, x3 = va.w + vb.w;
  float s = wred_add(x0 + x1 + x2 + x3);
  if (lane == 0) sm[w] = s;
  __syncthreads();
  float mu = (sm[0] + sm[1] + sm[2] + sm[3]) * (1.f / 1024.f);
  float d0 = x0 - mu, d1 = x1 - mu, d2 = x2 - mu, d3 = x3 - mu;
  float q = wred_add(d0 * d0 + d1 * d1 + d2 * d2 + d3 * d3);
  __syncthreads();
  if (lane == 0) sm[w] = q;
  __syncthreads();
  float var = (sm[0] + sm[1] + sm[2] + sm[3]) * (1.f / 1024.f);
  float rs = 1.f / sqrtf(var + 1e-5f);
  float4 g4 = ((const float4*)gm)[tid];
  float4 b4 = ((const float4*)bt)[tid];
  float4 o;
  o.x = d0 * rs * g4.x + b4.x;
  o.y = d1 * rs * g4.y + b4.y;
  o.z = d2 * rs * g4.z + b4.z;
  o.w = d3 * rs * g4.w + b4.w;
  ((float4*)(out + (int64_t)r * 1024))[tid] = o;
  // fused router: key = o . rw + rb
  float4 w4 = ((const float4*)rw)[tid];
  float p = o.x * w4.x + o.y * w4.y + o.z * w4.z + o.w * w4.w;
  p = wred_add(p);
  __syncthreads();
  if (lane == 0) sm[w] = p;
  __syncthreads();
  if (tid == 0) {
    float key = (sm[0] + sm[1] + sm[2] + sm[3]) + rb[0];
    eidx[r] = (int)floorf(key) & 3;  // two's-complement & 3 == floor-mod 4
  }
}

// ---------------- split-K reduce + bias + residual + LN2 + scatter (fused) ----------------
__global__ __launch_bounds__(256) void reduce_ln_k(const float* __restrict__ part, const int* __restrict__ rowsrc,
                                                   const int* __restrict__ ofs, const float* __restrict__ b2,
                                                   const float* __restrict__ xb, const float* __restrict__ gm,
                                                   const float* __restrict__ bt, float* __restrict__ out) {
  __shared__ float sm[4];
  const int r = blockIdx.x;
  if (r >= ofs[4]) return;
  const int s = rowsrc[r];
  if (s < 0) return;
  int e = 0;
  while (e < 3 && r >= ofs[e + 1]) ++e;
  const int tid = threadIdx.x, w = tid >> 6, lane = tid & 63;
  const int64_t RN = 2560ll * 1024;
  float4 v0 = ((const float4*)(part + 0 * RN + (int64_t)r * 1024))[tid];
  float4 v1 = ((const float4*)(part + 1 * RN + (int64_t)r * 1024))[tid];
  float4 bb = ((const float4*)(b2 + (int64_t)e * 1024))[tid];
  float4 va = ((const float4*)(xb + (int64_t)s * 1024))[tid];
  float y0 = (v0.x + v1.x) + bb.x, y1 = (v0.y + v1.y) + bb.y;
  float y2 = (v0.z + v1.z) + bb.z, y3 = (v0.w + v1.w) + bb.w;
  float x0 = va.x + y0, x1 = va.y + y1, x2 = va.z + y2, x3 = va.w + y3;
  float sum = wred_add(x0 + x1 + x2 + x3);
  if (lane == 0) sm[w] = sum;
  __syncthreads();
  float mu = (sm[0] + sm[1] + sm[2] + sm[3]) * (1.f / 1024.f);
  float d0 = x0 - mu, d1 = x1 - mu, d2 = x2 - mu, d3 = x3 - mu;
  float q = wred_add(d0 * d0 + d1 * d1 + d2 * d2 + d3 * d3);
  __syncthreads();
  if (lane == 0) sm[w] = q;
  __syncthreads();
  float var = (sm[0] + sm[1] + sm[2] + sm[3]) * (1.f / 1024.f);
  float rs = 1.f / sqrtf(var + 1e-5f);
  float4 g4 = ((const float4*)gm)[tid];
  float4 b4 = ((const float4*)bt)[tid];
  float4 o;
  o.x = d0 * rs * g4.x + b4.x;
  o.y = d1 * rs * g4.y + b4.y;
  o.z = d2 * rs * g4.z + b4.z;
  o.w = d3 * rs * g4.w + b4.w;
  ((float4*)(out + (int64_t)s * 1024))[tid] = o;
}

// ---------------- stable compaction ----------------
__global__ __launch_bounds__(256) void compact_k(const int* __restrict__ eidx,
                                                 int* __restrict__ rowsrc, int* __restrict__ ofs) {
  __shared__ unsigned long long sc[256];
  __shared__ int soff[5];
  const int tid = threadIdx.x;
  int myE[8];
  unsigned long long c = 0;
#pragma unroll
  for (int i = 0; i < 8; ++i) {
    int e = eidx[tid * 8 + i];
    myE[i] = e;
    c += 1ull << (e * 16);
  }
  sc[tid] = c;
  __syncthreads();
  for (int o = 1; o < 256; o <<= 1) {
    unsigned long long v = (tid >= o) ? sc[tid - o] : 0ull;
    __syncthreads();
    sc[tid] += v;
    __syncthreads();
  }
  unsigned long long incl = sc[tid], tot = sc[255];
  unsigned long long excl = incl - c;
  if (tid == 0) {
    int off = 0;
    for (int e = 0; e < 4; ++e) {
      soff[e] = off;
      int cnt = (int)((tot >> (e * 16)) & 0xffff);
      off += (cnt + 127) & ~127;
    }
    soff[4] = off;
    for (int e = 0; e < 5; ++e) ofs[e] = soff[e];
  }
  __syncthreads();
  for (int r = tid; r < 2560; r += 256) rowsrc[r] = -1;
  __threadfence_block();
  __syncthreads();
  int rank[4];
#pragma unroll
  for (int e = 0; e < 4; ++e) rank[e] = (int)((excl >> (e * 16)) & 0xffff);
#pragma unroll
  for (int i = 0; i < 8; ++i) {
    int e = myE[i];
    rowsrc[soff[e] + rank[e]] = tid * 8 + i;
    rank[e]++;
  }
}

// ---------------- gather x rows (f32 -> bf16, rho-permuted cols) ----------------
__global__ __launch_bounds__(256) void gather_k(const float* __restrict__ x, const int* __restrict__ rowsrc,
                                                const int* __restrict__ ofs, u16* __restrict__ xg) {
  int r = blockIdx.x;
  if (r >= ofs[4]) return;
  int s = rowsrc[r];
  int c = threadIdx.x;  // source quad index
  float4 v = (s >= 0) ? ((const float4*)(x + (int64_t)s * 1024))[c] : float4{0.f, 0.f, 0.f, 0.f};
  ushort4 o;
  o.x = f2bf(v.x); o.y = f2bf(v.y); o.z = f2bf(v.z); o.w = f2bf(v.w);
  int t = c & 7, blk = c >> 3;
  int si = blk * 8 + ((t & 3) << 1) + (t >> 2);
  ((ushort4*)(xg + (int64_t)r * 1024))[si] = o;
}

// ---------------- host ----------------
extern "C" void kernel_launch(void* const* d_in, const int* in_sizes, int n_in,
                              void* d_out, int out_size, void* d_ws, size_t ws_size,
                              hipStream_t stream) {
  const float* src = (const float*)d_in[0];
  const float* Wq  = (const float*)d_in[1];
  const float* bq  = (const float*)d_in[2];
  const float* Wk  = (const float*)d_in[3];
  const float* bk  = (const float*)d_in[4];
  const float* Wv  = (const float*)d_in[5];
  const float* bv  = (const float*)d_in[6];
  const float* Wo  = (const float*)d_in[7];
  const float* bo  = (const float*)d_in[8];
  const float* rw  = (const float*)d_in[9];
  const float* rb  = (const float*)d_in[10];
  const float* W1  = (const float*)d_in[11];
  const float* b1  = (const float*)d_in[12];
  const float* W2  = (const float*)d_in[13];
  const float* b2  = (const float*)d_in[14];
  const float* g1  = (const float*)d_in[15];
  const float* be1 = (const float*)d_in[16];
  const float* g2  = (const float*)d_in[17];
  const float* be2 = (const float*)d_in[18];
  float* out = (float*)d_out;

  char* base = (char*)d_ws;
  size_t off = 0;
  auto alloc = [&](size_t bytes) -> char* {
    char* p = base + off;
    off += (bytes + 255) & ~(size_t)255;
    return p;
  };
  const size_t MB = 1ull << 20;
  u16* srcH = (u16*)alloc(4 * MB);
  u16* srcL = (u16*)alloc(4 * MB);
  u16* WqkvTh = (u16*)alloc(6 * MB);
  u16* WqkvTl = (u16*)alloc(6 * MB);
  u16* WoTh = (u16*)alloc(2 * MB);
  u16* WoTl = (u16*)alloc(2 * MB);
  float* bqkv = (float*)alloc(16 * 1024);
  u16* qkvH = (u16*)alloc(12 * MB);
  u16* qkvL = (u16*)alloc(12 * MB);
  u16* hbuf = (u16*)qkvH;  // alias: 20MB over qkvH+qkvL (24MB), dead by FFN time
  u16* vTH = (u16*)alloc(4 * MB); u16* vTL = (u16*)alloc(4 * MB);
  float* scores = (float*)alloc(64 * MB);  // probs in place; later W1T/W2T
  u16* W1T = (u16*)scores;
  u16* W2T = (u16*)scores + 16ull * 1024 * 1024;
  u16* attnH = (u16*)alloc(4 * MB); u16* attnL = (u16*)alloc(4 * MB);
  u16* xg = (u16*)attnH;  // alias: 5MB over attnH+attnL (8MB), dead after Wo GEMM
  float* woOut = (float*)alloc(8 * MB);
  float* xbuf = (float*)alloc(8 * MB);
  float* partials = (float*)alloc(20 * MB);  // 2 x 2560 x 1024 f32
  int* eidx   = (int*)alloc(2048 * 4);
  int* rowsrc = (int*)alloc(2560 * 4);
  int* ofs    = (int*)alloc(32);
  (void)ws_size; (void)in_sizes; (void)n_in; (void)out_size;

  dim3 tb(32, 8);

  // Phase 0: splits / weight transposes (attention)
  split_k<<<2048, 256, 0, stream>>>(src, srcH, srcL, 2048 * 1024 / 4);
  transpose_split_k<true><<<dim3(8, 32, 1), tb, 0, stream>>>(Wq, 0, WqkvTh, WqkvTl, 0, 1024, 1024);
  transpose_split_k<true><<<dim3(8, 32, 1), tb, 0, stream>>>(Wk, 0, WqkvTh + 1024 * 1024, WqkvTl + 1024 * 1024, 0, 1024, 1024);
  transpose_split_k<true><<<dim3(8, 32, 1), tb, 0, stream>>>(Wv, 0, WqkvTh + 2 * 1024 * 1024, WqkvTl + 2 * 1024 * 1024, 0, 1024, 1024);
  transpose_split_k<true><<<dim3(8, 32, 1), tb, 0, stream>>>(Wo, 0, WoTh, WoTl, 0, 1024, 1024);
  catb_k<<<12, 256, 0, stream>>>(bq, bk, bv, bqkv);

  // Phase 1: fused QKV projection (bf16x3) -> qkv hi/lo [2048][3072], cols rho'd
  {
    GemmArgs g{};
    g.Ah = srcH; g.Al = srcL; g.lda = 1024;
    g.Bh = WqkvTh; g.Bl = WqkvTl; g.ldb = 1024;
    g.Ch = qkvH; g.Cl = qkvL; g.ldc = 3072;
    g.bias = bqkv; g.K = 1024; g.Z2 = 0;
    gemm_k<128, 96, true, 1, true, 2><<<dim3(16, 32, 1), 256, 0, stream>>>(g);
  }
  // v slice -> vT [b][d][t] hi/lo (lossless re-layout, t rho'd)
  transpose_pair_k<<<dim3(32, 16, 4), tb, 0, stream>>>(qkvH, qkvL, vTH, vTL);

  // Phase 2: scores = q @ k^T (bf16x3), batched over (b,h), t-cols rho'd
  {
    GemmArgs g{};
    g.Ah = qkvH; g.Al = qkvL; g.lda = 3072;
    g.Bh = qkvH + 1024; g.Bl = qkvL + 1024; g.ldb = 3072;
    g.C = scores; g.ldc = 512;
    g.K = 64; g.Z2 = 16;
    g.aZ1 = 512ll * 3072; g.aZ2 = 64;
    g.bZ1 = 512ll * 3072; g.bZ2 = 64;
    g.cZ1 = 16ll * 512 * 512; g.cZ2 = 512ll * 512;
    gemm_k<128, 64, true, 0, true, 3><<<dim3(4, 8, 64), 256, 0, stream>>>(g);
  }
  softmax_k<<<64 * 512, 128, 0, stream>>>(scores);
  // PV: attn = probs @ v (bf16x3) -> attn hi/lo, d-cols rho'd
  {
    GemmArgs g{};
    g.Ah = (const u16*)scores; g.Al = (const u16*)scores + 512; g.lda = 1024;
    g.Bh = vTH; g.Bl = vTL; g.ldb = 512;
    g.Ch = attnH; g.Cl = attnL; g.ldc = 1024;
    g.K = 512; g.Z2 = 16;
    g.aZ1 = 16ll * 512 * 1024; g.aZ2 = 512ll * 1024;
    g.bZ1 = 1024ll * 512;      g.bZ2 = 64ll * 512;
    g.cZ1 = 512ll * 1024;      g.cZ2 = 64;
    gemm_k<64, 64, true, 1, true, 3><<<dim3(8, 1, 64), 256, 0, stream>>>(g);
  }
  // Wo projection (bf16x3) + bias -> plain f32 (feeds LN/residual)
  {
    GemmArgs g{};
    g.Ah = attnH; g.Al = attnL; g.lda = 1024;
    g.Bh = WoTh; g.Bl = WoTl; g.ldb = 1024;
    g.C = woOut; g.ldc = 1024;
    g.bias = bo; g.K = 1024; g.Z2 = 0;
    gemm_k<64, 64, true, 0, false, 3><<<dim3(32, 16, 1), 256, 0, stream>>>(g);
  }
  // ln1 + fused router
  ln_router_k<<<2048, 256, 0, stream>>>(src, woOut, g1, be1, rw, rb, xbuf, eidx);

  // Phase 3: routing
  compact_k<<<1, 256, 0, stream>>>(eidx, rowsrc, ofs);
  gather_k<<<2560, 256, 0, stream>>>(xbuf, rowsrc, ofs, xg);

  // FFN weights -> bf16 transposed (into dead scores region), k-dims rho'd
  transpose_split_k<false><<<dim3(32, 32, 4), tb, 0, stream>>>(W1, 1024ll * 4096, W1T, nullptr, 4096ll * 1024, 1024, 4096);
  transpose_split_k<false><<<dim3(8, 128, 4), tb, 0, stream>>>(W2, 4096ll * 1024, W2T, nullptr, 1024ll * 4096, 4096, 1024);

  // FFN1: h = relu(xg @ W1[e] + b1[e]) -> bf16, cols rho'd
  {
    GemmArgs g{};
    g.Ah = xg; g.lda = 1024;
    g.Bh = W1T; g.ldb = 1024;
    g.Ch = hbuf; g.ldc = 4096;
    g.bias = b1; g.biasStrE = 4096;
    g.K = 1024; g.Z2 = 0;
    g.ofs = ofs; g.bStrE = 4096ll * 1024;
    gemm_k<128, 128, false, 2, true, 3><<<dim3(20, 32, 1), 256, 0, stream>>>(g);
  }
  // FFN2 split-K x2: partial[c] = h[:, c*2048:(c+1)*2048] @ W2[e][c*2048:..., :]
  {
    GemmArgs g{};
    g.Ah = hbuf; g.lda = 4096;
    g.Bh = W2T; g.ldb = 4096;
    g.C = partials; g.ldc = 1024;
    g.bias = nullptr;
    g.K = 2048; g.Z2 = 2;
    g.aZ1 = 0; g.aZ2 = 2048;       // K-chunk offset within A row
    g.bZ1 = 0; g.bZ2 = 2048;       // K-chunk offset within B row
    g.cZ1 = 0; g.cZ2 = 2560ll * 1024;
    g.ofs = ofs; g.bStrE = 4096ll * 1024;
    gemm_k<128, 64, false, 0, false, 3><<<dim3(20, 16, 2), 256, 0, stream>>>(g);
  }
  // fused: reduce split-K + b2 + residual + LN2 + scatter to out
  reduce_ln_k<<<2560, 256, 0, stream>>>(partials, rowsrc, ofs, b2, xbuf, g2, be2, out);
}

// Round 8
// 299.289 us; speedup vs baseline: 1.0571x; 1.0363x over previous
//
#include <hip/hip_runtime.h>
#include <hip/hip_bf16.h>
#include <stdint.h>

typedef unsigned short u16;
typedef __attribute__((ext_vector_type(8))) short s8v;
typedef __attribute__((ext_vector_type(4))) float f4v;

#define DEVI static __device__ __forceinline__

DEVI u16 f2bf(float x) {
  union { float f; unsigned u; } a; a.f = x;
  return (u16)((a.u + 0x7fffu + ((a.u >> 16) & 1u)) >> 16);  // RNE
}
DEVI float bf2f(u16 h) {
  union { float f; unsigned u; } a; a.u = ((unsigned)h) << 16; return a.f;
}
DEVI float wred_add(float s) {
#pragma unroll
  for (int o = 32; o; o >>= 1) s += __shfl_xor(s, o, 64);
  return s;
}
DEVI float wred_max(float s) {
#pragma unroll
  for (int o = 32; o; o >>= 1) s = fmaxf(s, __shfl_xor(s, o, 64));
  return s;
}
DEVI f4v mfma16(s8v a, s8v b, f4v c) {
  return __builtin_amdgcn_mfma_f32_16x16x32_bf16(a, b, c, 0, 0, 0);
}

// rho: within each 32-elem k-block, source elem j is STORED at position rho(j).
// Stored granule g (16B) = source elems {4g..4g+3, 16+4g..16+4g+3} == the MFMA
// k-slot set used since round 1 -> bitwise-identical MFMA inputs.
// rho(4g+i) = rho(4g)+i  (4-consecutive stays contiguous).
DEVI int rho(int j) { return ((j & 12) << 1) | (j & 3) | ((j >> 4) << 2); }

// async global->LDS, 16B per lane; LDS base wave-uniform, HW writes base+lane*16
DEVI void gload16(const u16* gp, u16* lp) {
  __builtin_amdgcn_global_load_lds(
      (const __attribute__((address_space(1))) uint32_t*)gp,
      (__attribute__((address_space(3))) uint32_t*)lp, 16, 0, 0);
}

// frag read: ONE ds_read_b128. LDS chunk = 16 rows x 64B; slot(r,lg) XOR-swizzled
// -> uniform 8 lanes/bank-quad, distinct addrs (verified r4-r7: BANK_CONFLICT == 0).
DEVI s8v ldfrag_sw(const u16* base, int r, int lg) {
  int off = ((r >> 4) << 9) + ((r & 15) << 5) + ((lg ^ ((r >> 1) & 3)) << 3);
  return *(const s8v*)(base + off);
}

// ---------------- elementwise split f32 -> bf16 hi/lo (rho-permuted cols) ----------------
__global__ __launch_bounds__(256) void split_k(const float* __restrict__ in,
                                               u16* __restrict__ h, u16* __restrict__ l, int n4) {
  int i = blockIdx.x * 256 + threadIdx.x;
  if (i >= n4) return;
  float4 v = ((const float4*)in)[i];
  ushort4 hv, lv;
  hv.x = f2bf(v.x); lv.x = f2bf(v.x - bf2f(hv.x));
  hv.y = f2bf(v.y); lv.y = f2bf(v.y - bf2f(hv.y));
  hv.z = f2bf(v.z); lv.z = f2bf(v.z - bf2f(hv.z));
  hv.w = f2bf(v.w); lv.w = f2bf(v.w - bf2f(hv.w));
  int t = i & 7, blk = i >> 3;
  int si = blk * 8 + ((t & 3) << 1) + (t >> 2);  // ushort4 slot of rho(4t)
  ((ushort4*)h)[si] = hv;
  ((ushort4*)l)[si] = lv;
}

// ---------------- transpose + split: f32 [z][R][C] -> bf16 [z][C][R], R rho'd ----------------
// vectorized: 32x128 tile, float4 loads, ushort4 stores
template<bool LO>
__global__ __launch_bounds__(256) void transpose_split_k(const float* __restrict__ in, long long zIn,
                                                         u16* __restrict__ outH, u16* __restrict__ outL,
                                                         long long zOut, int R, int C) {
  __shared__ float t[32][132];
  in += (long long)blockIdx.z * zIn;
  outH += (long long)blockIdx.z * zOut;
  if (LO) outL += (long long)blockIdx.z * zOut;
  const int cc = blockIdx.x * 128, rr = blockIdx.y * 32;
  const int id = threadIdx.y * 32 + threadIdx.x;  // (32,8) -> 0..255
#pragma unroll
  for (int i = 0; i < 4; ++i) {
    int slot = i * 256 + id;                 // 0..1023
    int r = slot >> 5, c4 = slot & 31;
    float4 v = *(const float4*)&in[(long long)(rr + r) * C + cc + c4 * 4];
    *(float4*)&t[r][c4 * 4] = v;
  }
  __syncthreads();
#pragma unroll
  for (int i = 0; i < 4; ++i) {
    int slot = i * 256 + id;
    int j = slot >> 3, gs = slot & 7;        // j: source col-in-tile, gs: 4-row group
    int r0 = gs * 4;
    float v0 = t[r0 + 0][j], v1 = t[r0 + 1][j], v2 = t[r0 + 2][j], v3 = t[r0 + 3][j];
    // stored base for rho(4*gs): 8*(gs&3) + 4*(gs>>2); rho keeps +0..3 contiguous
    long long o = (long long)(cc + j) * R + rr + 8 * (gs & 3) + 4 * (gs >> 2);
    ushort4 hv;
    hv.x = f2bf(v0); hv.y = f2bf(v1); hv.z = f2bf(v2); hv.w = f2bf(v3);
    *(ushort4*)&outH[o] = hv;
    if (LO) {
      ushort4 lv;
      lv.x = f2bf(v0 - bf2f(hv.x)); lv.y = f2bf(v1 - bf2f(hv.y));
      lv.z = f2bf(v2 - bf2f(hv.z)); lv.w = f2bf(v3 - bf2f(hv.w));
      *(ushort4*)&outL[o] = lv;
    }
  }
}

// ---------------- bf16-pair transpose (vectorized): v slice of qkv -> vT [b][d][t] ----------------
// in cols rho'd (d), out t rho'd. ushort4 both sides; rho keeps 4-runs contiguous.
__global__ __launch_bounds__(256) void transpose_pair_k(const u16* __restrict__ inH, const u16* __restrict__ inL,
                                                        u16* __restrict__ oH, u16* __restrict__ oL) {
  __shared__ u16 th[32][40], tl[32][40];  // 80B rows: 8B-aligned quads, <=2-way banks
  const int b = blockIdx.z;
  const int dd = blockIdx.x * 32;   // d in [0,1024)
  const int tt = blockIdx.y * 32;   // t in [0,512)
  const int id = threadIdx.y * 32 + threadIdx.x;  // 0..255
  const int rr = id >> 3, g = id & 7;
  const int rg = 8 * (g & 3) + 4 * (g >> 2);      // rho(4g)
  const int64_t ibase = ((int64_t)(b * 512 + tt)) * 3072 + 2048 + dd;
  // load: stored cols rg..rg+3 == source d = dd+4g..+3, row t = tt+rr
  ushort4 hv = *(const ushort4*)&inH[ibase + (int64_t)rr * 3072 + rg];
  ushort4 lv = *(const ushort4*)&inL[ibase + (int64_t)rr * 3072 + rg];
  *(ushort4*)&th[rr][4 * g] = hv;   // th[t][d] source order
  *(ushort4*)&tl[rr][4 * g] = lv;
  __syncthreads();
  // write: out row d = dd+j; 4 source t's {4g..4g+3} at stored positions rho(4g)..+3
  const int j = rr;  // reuse decomposition: j 0..31, g 0..7
  ushort4 ho, lo;
  ho.x = th[4 * g + 0][j]; ho.y = th[4 * g + 1][j]; ho.z = th[4 * g + 2][j]; ho.w = th[4 * g + 3][j];
  lo.x = tl[4 * g + 0][j]; lo.y = tl[4 * g + 1][j]; lo.z = tl[4 * g + 2][j]; lo.w = tl[4 * g + 3][j];
  const int64_t obase = ((int64_t)b * 1024 + dd + j) * 512 + tt + rg;
  *(ushort4*)&oH[obase] = ho;
  *(ushort4*)&oL[obase] = lo;
}

// ---------------- concat q,k,v biases ----------------
__global__ __launch_bounds__(256) void catb_k(const float* __restrict__ a, const float* __restrict__ b,
                                              const float* __restrict__ c, float* __restrict__ o) {
  int i = blockIdx.x * 256 + threadIdx.x;
  if (i >= 3072) return;
  o[i] = i < 1024 ? a[i] : (i < 2048 ? b[i - 1024] : c[i - 2048]);
}

// ---------------- generic MFMA GEMM: counted-vmcnt pipeline (+ optional XCD swizzle) ----------------
// C[M,N] = A[M,K] @ B^T[N,K] (+bias). SPLIT: hi+lo bf16, 3 MFMAs (drop lo*lo).
// EPI: 0=f32(+bias), 1=split hi/lo bf16(+bias), 2=relu->bf16(+bias)
// PN: write C columns rho-permuted. SWZ: 1D grid, XCD-chunked, by-fast-in-YG decode.
struct GemmArgs {
  const u16* Ah; const u16* Al; int lda;
  const u16* Bh; const u16* Bl; int ldb;
  float* C; u16* Ch; u16* Cl; int ldc;
  const float* bias;
  int K;
  int Z2;  // 0 = unbatched
  int64_t aZ1, aZ2, bZ1, bZ2, cZ1, cZ2;
  const int* ofs;      // [5], non-null => per-row-tile expert select
  int64_t bStrE; int biasStrE;
  int NX, NY, YG;      // SWZ decode params
};

template<int BM, int BN, bool SPLIT, int EPI, bool PN, int MINW, bool SWZ>
__global__ __launch_bounds__(256, MINW) void gemm_k(GemmArgs g) {
  constexpr int ASZ = BM * 32, BSZ = BN * 32;
  constexpr int AN = SPLIT ? 2 * ASZ : ASZ;
  constexpr int BNT = SPLIT ? 2 * BSZ : BSZ;
  constexpr int nA = BM / 16, nB = BN / 16;
  constexpr int nAt = SPLIT ? 2 * nA : nA;
  constexpr int TOT = nAt + (SPLIT ? 2 * nB : nB);
  static_assert(TOT % 4 == 0, "chunk count must divide across 4 waves");
  constexpr int NLOAD = TOT / 4;  // gloads per lane per stage
  __shared__ __align__(16) u16 sA[2][AN];
  __shared__ __align__(16) u16 sB[2][BNT];

  const int tid = threadIdx.x;
  int bx, by, bz;
  if (SWZ) {
    // XCD-bijective remap (nwg % 8 == 0): each XCD gets a contiguous wg chunk
    const int nwg = gridDim.x;
    int wg = (blockIdx.x & 7) * (nwg >> 3) + (blockIdx.x >> 3);
    int byl = wg % g.YG; int t = wg / g.YG;
    bx = t % g.NX; t /= g.NX;
    const int nyg = g.NY / g.YG;
    by = (t % nyg) * g.YG + byl;
    bz = t / nyg;
  } else {
    bx = blockIdx.x; by = blockIdx.y; bz = blockIdx.z;
  }

  const u16* Ah = g.Ah; const u16* Al = g.Al;
  const u16* Bh = g.Bh; const u16* Bl = g.Bl;
  int64_t cOff = 0;
  if (g.Z2 > 0) {
    int z1 = bz / g.Z2, z2 = bz % g.Z2;
    int64_t ao = (int64_t)z1 * g.aZ1 + (int64_t)z2 * g.aZ2;
    int64_t bo = (int64_t)z1 * g.bZ1 + (int64_t)z2 * g.bZ2;
    Ah += ao; Bh += bo;
    if (SPLIT) { Al += ao; Bl += bo; }
    cOff = (int64_t)z1 * g.cZ1 + (int64_t)z2 * g.cZ2;
  }
  const int row0 = bx * BM;
  const int col0 = by * BN;
  const float* bias = g.bias;
  if (g.ofs) {
    if (row0 >= g.ofs[4]) return;
    int e = 0;
    while (e < 3 && row0 >= g.ofs[e + 1]) ++e;
    Bh += (int64_t)e * g.bStrE;
    if (bias) bias += (int64_t)e * g.biasStrE;
  }

  const int w = tid >> 6, lane = tid & 63;
  const int wr = w >> 1, wc = w & 1;
  const int lr = lane & 15, lg = lane >> 4;
  constexpr int FM = BM / 32, FN = BN / 32;

  // staging: lane L stores LDS slot L; fetches global granule (L&3)^((L>>3)&3)
  const int srow = lane >> 2;
  const int sG = (lane & 3) ^ ((lane >> 3) & 3);

  auto stage = [&](int b, int kt) {
#pragma unroll
    for (int c = 0; c < NLOAD; ++c) {
      int s = c * 4 + w;  // wave-uniform slot id
      if (s < nA) {
        int64_t go = (int64_t)(row0 + s * 16 + srow) * g.lda + kt + sG * 8;
        gload16(Ah + go, &sA[b][s * 512]);
      } else if (SPLIT && s < 2 * nA) {
        int ch = s - nA;
        int64_t go = (int64_t)(row0 + ch * 16 + srow) * g.lda + kt + sG * 8;
        gload16(Al + go, &sA[b][ASZ + ch * 512]);
      } else if (s < nAt + nB) {
        int ch = s - nAt;
        int64_t go = (int64_t)(col0 + ch * 16 + srow) * g.ldb + kt + sG * 8;
        gload16(Bh + go, &sB[b][ch * 512]);
      } else {
        int ch = s - nAt - nB;
        int64_t go = (int64_t)(col0 + ch * 16 + srow) * g.ldb + kt + sG * 8;
        gload16(Bl + go, &sB[b][BSZ + ch * 512]);
      }
    }
  };

  f4v acc[FM][FN];
#pragma unroll
  for (int i = 0; i < FM; ++i)
#pragma unroll
    for (int j = 0; j < FN; ++j) acc[i][j] = f4v{0.f, 0.f, 0.f, 0.f};

  s8v a0[FM], b0[FN], al0[SPLIT ? FM : 1], bl0[SPLIT ? FN : 1];
  s8v a1[FM], b1[FN], al1[SPLIT ? FM : 1], bl1[SPLIT ? FN : 1];

  auto rdfrags = [&](int buf, auto& af, auto& bf, auto& afl, auto& bfl) {
#pragma unroll
    for (int mi = 0; mi < FM; ++mi) {
      int r = wr * (BM / 2) + mi * 16 + lr;
      af[mi] = ldfrag_sw(&sA[buf][0], r, lg);
      if (SPLIT) afl[mi] = ldfrag_sw(&sA[buf][ASZ], r, lg);
    }
#pragma unroll
    for (int ni = 0; ni < FN; ++ni) {
      int r = wc * (BN / 2) + ni * 16 + lr;
      bf[ni] = ldfrag_sw(&sB[buf][0], r, lg);
      if (SPLIT) bfl[ni] = ldfrag_sw(&sB[buf][BSZ], r, lg);
    }
  };

  const int nt = g.K >> 5;

  stage(0, 0);
  stage(1, 32);
  asm volatile("s_waitcnt vmcnt(%0)" :: "n"(NLOAD) : "memory");  // buf0 landed
  __builtin_amdgcn_sched_barrier(0);
  __builtin_amdgcn_s_barrier();
  rdfrags(0, a0, b0, al0, bl0);

  auto body = [&](int t, auto& cA, auto& cB, auto& cAl, auto& cBl,
                  auto& nA_, auto& nB_, auto& nAl_, auto& nBl_) {
    asm volatile("s_waitcnt lgkmcnt(0)" ::: "memory");
    __builtin_amdgcn_sched_barrier(0);
    __builtin_amdgcn_s_barrier();
    if (t + 2 < nt) stage(t & 1, (t + 2) << 5);  // overwrite just-freed buffer
    if (t + 1 < nt) {
      if (t + 2 < nt)
        asm volatile("s_waitcnt vmcnt(%0)" :: "n"(NLOAD) : "memory");  // stage(t+1) done
      else
        asm volatile("s_waitcnt vmcnt(0)" ::: "memory");
      __builtin_amdgcn_sched_barrier(0);
      __builtin_amdgcn_s_barrier();
      rdfrags((t + 1) & 1, nA_, nB_, nAl_, nBl_);  // next-step ds_reads...
    }
    __builtin_amdgcn_sched_barrier(0);  // ...pinned BEFORE the MFMA cluster
    __builtin_amdgcn_s_setprio(1);
#pragma unroll
    for (int mi = 0; mi < FM; ++mi)
#pragma unroll
      for (int ni = 0; ni < FN; ++ni) {
        acc[mi][ni] = mfma16(cA[mi], cB[ni], acc[mi][ni]);
        if (SPLIT) {
          acc[mi][ni] = mfma16(cA[mi], cBl[ni], acc[mi][ni]);
          acc[mi][ni] = mfma16(cAl[mi], cB[ni], acc[mi][ni]);
        }
      }
    __builtin_amdgcn_s_setprio(0);
  };

  for (int t = 0; t < nt; t += 2) {
    body(t,     a0, b0, al0, bl0, a1, b1, al1, bl1);
    body(t + 1, a1, b1, al1, bl1, a0, b0, al0, bl0);
  }

  // epilogue (C/D frag: col=lane&15, row=(lane>>4)*4+j — HW-verified layout)
#pragma unroll
  for (int mi = 0; mi < FM; ++mi) {
    int rbase = row0 + wr * (BM / 2) + mi * 16 + lg * 4;
#pragma unroll
    for (int ni = 0; ni < FN; ++ni) {
      int c = col0 + wc * (BN / 2) + ni * 16 + lr;  // source column (bias index)
      int cs = PN ? ((c & ~31) | rho(c & 31)) : c;  // stored position
      float bv = bias ? bias[c] : 0.f;
#pragma unroll
      for (int j = 0; j < 4; ++j) {
        int r = rbase + j;
        float v = acc[mi][ni][j] + bv;
        if (EPI == 0) {
          g.C[cOff + (int64_t)r * g.ldc + cs] = v;
        } else if (EPI == 1) {
          u16 h = f2bf(v);
          int64_t o = cOff + (int64_t)r * g.ldc + cs;
          g.Ch[o] = h;
          g.Cl[o] = f2bf(v - bf2f(h));
        } else {
          v = v > 0.f ? v : 0.f;
          g.Ch[cOff + (int64_t)r * g.ldc + cs] = f2bf(v);
        }
      }
    }
  }
}

// ---------------- softmax over 512 cols (position-oblivious), probs hi/lo IN PLACE ----------------
__global__ __launch_bounds__(128) void softmax_k(float* __restrict__ scores) {
  __shared__ float sm[2];
  const int64_t row = blockIdx.x;
  float* p = scores + row * 512;
  const int tid = threadIdx.x, w = tid >> 6, lane = tid & 63;
  float4 v = ((const float4*)p)[tid];
  v.x *= 0.125f; v.y *= 0.125f; v.z *= 0.125f; v.w *= 0.125f;
  float m = wred_max(fmaxf(fmaxf(v.x, v.y), fmaxf(v.z, v.w)));
  if (lane == 0) sm[w] = m;
  __syncthreads();
  m = fmaxf(sm[0], sm[1]);
  float e0 = expf(v.x - m), e1 = expf(v.y - m), e2 = expf(v.z - m), e3 = expf(v.w - m);
  float s = wred_add(e0 + e1 + e2 + e3);
  __syncthreads();
  if (lane == 0) sm[w] = s;
  __syncthreads();
  float inv = 1.f / (sm[0] + sm[1]);
  e0 *= inv; e1 *= inv; e2 *= inv; e3 *= inv;
  u16* ph = (u16*)p;  // row's own 2KB: hi at [0,512), lo at [512,1024) bf16 elems
  ushort4 hv, lv;
  hv.x = f2bf(e0); lv.x = f2bf(e0 - bf2f(hv.x));
  hv.y = f2bf(e1); lv.y = f2bf(e1 - bf2f(hv.y));
  hv.z = f2bf(e2); lv.z = f2bf(e2 - bf2f(hv.z));
  hv.w = f2bf(e3); lv.w = f2bf(e3 - bf2f(hv.w));
  ((ushort4*)ph)[tid] = hv;
  ((ushort4*)(ph + 512))[tid] = lv;
}

// ---------------- residual + layernorm + fused router ----------------
__global__ __launch_bounds__(256) void ln_router_k(const float* __restrict__ a, const float* __restrict__ b,
                                                   const float* __restrict__ gm, const float* __restrict__ bt,
                                                   const float* __restrict__ rw, const float* __restrict__ rb,
                                                   float* __restrict__ out, int* __restrict__ eidx) {
  __shared__ float sm[4];
  const int r = blockIdx.x, tid = threadIdx.x;
  const int w = tid >> 6, lane = tid & 63;
  float4 va = ((const float4*)(a + (int64_t)r * 1024))[tid];
  float4 vb = ((const float4*)(b + (int64_t)r * 1024))[tid];
  float x0 = va.x + vb.x, x1 = va.y + vb.y, x2 = va.z + vb.z, x3 = va.w + vb.w;
  float s = wred_add(x0 + x1 + x2 + x3);
  if (lane == 0) sm[w] = s;
  __syncthreads();
  float mu = (sm[0] + sm[1] + sm[2] + sm[3]) * (1.f / 1024.f);
  float d0 = x0 - mu, d1 = x1 - mu, d2 = x2 - mu, d3 = x3 - mu;
  float q = wred_add(d0 * d0 + d1 * d1 + d2 * d2 + d3 * d3);
  __syncthreads();
  if (lane == 0) sm[w] = q;
  __syncthreads();
  float var = (sm[0] + sm[1] + sm[2] + sm[3]) * (1.f / 1024.f);
  float rs = 1.f / sqrtf(var + 1e-5f);
  float4 g4 = ((const float4*)gm)[tid];
  float4 b4 = ((const float4*)bt)[tid];
  float4 o;
  o.x = d0 * rs * g4.x + b4.x;
  o.y = d1 * rs * g4.y + b4.y;
  o.z = d2 * rs * g4.z + b4.z;
  o.w = d3 * rs * g4.w + b4.w;
  ((float4*)(out + (int64_t)r * 1024))[tid] = o;
  float4 w4 = ((const float4*)rw)[tid];
  float p = o.x * w4.x + o.y * w4.y + o.z * w4.z + o.w * w4.w;
  p = wred_add(p);
  __syncthreads();
  if (lane == 0) sm[w] = p;
  __syncthreads();
  if (tid == 0) {
    float key = (sm[0] + sm[1] + sm[2] + sm[3]) + rb[0];
    eidx[r] = (int)floorf(key) & 3;  // two's-complement & 3 == floor-mod 4
  }
}

// ---------------- split-K reduce + bias + residual + LN2 + scatter (fused) ----------------
__global__ __launch_bounds__(256) void reduce_ln_k(const float* __restrict__ part, const int* __restrict__ rowsrc,
                                                   const int* __restrict__ ofs, const float* __restrict__ b2,
                                                   const float* __restrict__ xb, const float* __restrict__ gm,
                                                   const float* __restrict__ bt, float* __restrict__ out) {
  __shared__ float sm[4];
  const int r = blockIdx.x;
  if (r >= ofs[4]) return;
  const int s = rowsrc[r];
  if (s < 0) return;
  int e = 0;
  while (e < 3 && r >= ofs[e + 1]) ++e;
  const int tid = threadIdx.x, w = tid >> 6, lane = tid & 63;
  const int64_t RN = 2560ll * 1024;
  float4 v0 = ((const float4*)(part + 0 * RN + (int64_t)r * 1024))[tid];
  float4 v1 = ((const float4*)(part + 1 * RN + (int64_t)r * 1024))[tid];
  float4 bb = ((const float4*)(b2 + (int64_t)e * 1024))[tid];
  float4 va = ((const float4*)(xb + (int64_t)s * 1024))[tid];
  float y0 = (v0.x + v1.x) + bb.x, y1 = (v0.y + v1.y) + bb.y;
  float y2 = (v0.z + v1.z) + bb.z, y3 = (v0.w + v1.w) + bb.w;
  float x0 = va.x + y0, x1 = va.y + y1, x2 = va.z + y2, x3 = va.w + y3;
  float sum = wred_add(x0 + x1 + x2 + x3);
  if (lane == 0) sm[w] = sum;
  __syncthreads();
  float mu = (sm[0] + sm[1] + sm[2] + sm[3]) * (1.f / 1024.f);
  float d0 = x0 - mu, d1 = x1 - mu, d2 = x2 - mu, d3 = x3 - mu;
  float q = wred_add(d0 * d0 + d1 * d1 + d2 * d2 + d3 * d3);
  __syncthreads();
  if (lane == 0) sm[w] = q;
  __syncthreads();
  float var = (sm[0] + sm[1] + sm[2] + sm[3]) * (1.f / 1024.f);
  float rs = 1.f / sqrtf(var + 1e-5f);
  float4 g4 = ((const float4*)gm)[tid];
  float4 b4 = ((const float4*)bt)[tid];
  float4 o;
  o.x = d0 * rs * g4.x + b4.x;
  o.y = d1 * rs * g4.y + b4.y;
  o.z = d2 * rs * g4.z + b4.z;
  o.w = d3 * rs * g4.w + b4.w;
  ((float4*)(out + (int64_t)s * 1024))[tid] = o;
}

// ---------------- stable compaction ----------------
__global__ __launch_bounds__(256) void compact_k(const int* __restrict__ eidx,
                                                 int* __restrict__ rowsrc, int* __restrict__ ofs) {
  __shared__ unsigned long long sc[256];
  __shared__ int soff[5];
  const int tid = threadIdx.x;
  int myE[8];
  unsigned long long c = 0;
#pragma unroll
  for (int i = 0; i < 8; ++i) {
    int e = eidx[tid * 8 + i];
    myE[i] = e;
    c += 1ull << (e * 16);
  }
  sc[tid] = c;
  __syncthreads();
  for (int o = 1; o < 256; o <<= 1) {
    unsigned long long v = (tid >= o) ? sc[tid - o] : 0ull;
    __syncthreads();
    sc[tid] += v;
    __syncthreads();
  }
  unsigned long long incl = sc[tid], tot = sc[255];
  unsigned long long excl = incl - c;
  if (tid == 0) {
    int off = 0;
    for (int e = 0; e < 4; ++e) {
      soff[e] = off;
      int cnt = (int)((tot >> (e * 16)) & 0xffff);
      off += (cnt + 127) & ~127;
    }
    soff[4] = off;
    for (int e = 0; e < 5; ++e) ofs[e] = soff[e];
  }
  __syncthreads();
  for (int r = tid; r < 2560; r += 256) rowsrc[r] = -1;
  __threadfence_block();
  __syncthreads();
  int rank[4];
#pragma unroll
  for (int e = 0; e < 4; ++e) rank[e] = (int)((excl >> (e * 16)) & 0xffff);
#pragma unroll
  for (int i = 0; i < 8; ++i) {
    int e = myE[i];
    rowsrc[soff[e] + rank[e]] = tid * 8 + i;
    rank[e]++;
  }
}

// ---------------- gather x rows (f32 -> bf16, rho-permuted cols) ----------------
__global__ __launch_bounds__(256) void gather_k(const float* __restrict__ x, const int* __restrict__ rowsrc,
                                                const int* __restrict__ ofs, u16* __restrict__ xg) {
  int r = blockIdx.x;
  if (r >= ofs[4]) return;
  int s = rowsrc[r];
  int c = threadIdx.x;  // source quad index
  float4 v = (s >= 0) ? ((const float4*)(x + (int64_t)s * 1024))[c] : float4{0.f, 0.f, 0.f, 0.f};
  ushort4 o;
  o.x = f2bf(v.x); o.y = f2bf(v.y); o.z = f2bf(v.z); o.w = f2bf(v.w);
  int t = c & 7, blk = c >> 3;
  int si = blk * 8 + ((t & 3) << 1) + (t >> 2);
  ((ushort4*)(xg + (int64_t)r * 1024))[si] = o;
}

// ---------------- host ----------------
extern "C" void kernel_launch(void* const* d_in, const int* in_sizes, int n_in,
                              void* d_out, int out_size, void* d_ws, size_t ws_size,
                              hipStream_t stream) {
  const float* src = (const float*)d_in[0];
  const float* Wq  = (const float*)d_in[1];
  const float* bq  = (const float*)d_in[2];
  const float* Wk  = (const float*)d_in[3];
  const float* bk  = (const float*)d_in[4];
  const float* Wv  = (const float*)d_in[5];
  const float* bv  = (const float*)d_in[6];
  const float* Wo  = (const float*)d_in[7];
  const float* bo  = (const float*)d_in[8];
  const float* rw  = (const float*)d_in[9];
  const float* rb  = (const float*)d_in[10];
  const float* W1  = (const float*)d_in[11];
  const float* b1  = (const float*)d_in[12];
  const float* W2  = (const float*)d_in[13];
  const float* b2  = (const float*)d_in[14];
  const float* g1  = (const float*)d_in[15];
  const float* be1 = (const float*)d_in[16];
  const float* g2  = (const float*)d_in[17];
  const float* be2 = (const float*)d_in[18];
  float* out = (float*)d_out;

  char* base = (char*)d_ws;
  size_t off = 0;
  auto alloc = [&](size_t bytes) -> char* {
    char* p = base + off;
    off += (bytes + 255) & ~(size_t)255;
    return p;
  };
  const size_t MB = 1ull << 20;
  u16* srcH = (u16*)alloc(4 * MB);
  u16* srcL = (u16*)alloc(4 * MB);
  u16* WqkvTh = (u16*)alloc(6 * MB);
  u16* WqkvTl = (u16*)alloc(6 * MB);
  u16* WoTh = (u16*)alloc(2 * MB);
  u16* WoTl = (u16*)alloc(2 * MB);
  float* bqkv = (float*)alloc(16 * 1024);
  u16* qkvH = (u16*)alloc(12 * MB);
  u16* qkvL = (u16*)alloc(12 * MB);
  u16* hbuf = (u16*)qkvH;  // alias: 20MB over qkvH+qkvL (24MB), dead by FFN time
  u16* vTH = (u16*)alloc(4 * MB); u16* vTL = (u16*)alloc(4 * MB);
  float* scores = (float*)alloc(64 * MB);  // probs in place; later W1T/W2T
  u16* W1T = (u16*)scores;
  u16* W2T = (u16*)scores + 16ull * 1024 * 1024;
  u16* attnH = (u16*)alloc(4 * MB); u16* attnL = (u16*)alloc(4 * MB);
  u16* xg = (u16*)attnH;  // alias: 5MB over attnH+attnL (8MB), dead after Wo GEMM
  float* woOut = (float*)alloc(8 * MB);
  float* xbuf = (float*)alloc(8 * MB);
  float* partials = (float*)alloc(20 * MB);  // 2 x 2560 x 1024 f32
  int* eidx   = (int*)alloc(2048 * 4);
  int* rowsrc = (int*)alloc(2560 * 4);
  int* ofs    = (int*)alloc(32);
  (void)ws_size; (void)in_sizes; (void)n_in; (void)out_size;

  dim3 tb(32, 8);

  // Phase 0: splits / weight transposes (attention)
  split_k<<<2048, 256, 0, stream>>>(src, srcH, srcL, 2048 * 1024 / 4);
  transpose_split_k<true><<<dim3(8, 32, 1), tb, 0, stream>>>(Wq, 0, WqkvTh, WqkvTl, 0, 1024, 1024);
  transpose_split_k<true><<<dim3(8, 32, 1), tb, 0, stream>>>(Wk, 0, WqkvTh + 1024 * 1024, WqkvTl + 1024 * 1024, 0, 1024, 1024);
  transpose_split_k<true><<<dim3(8, 32, 1), tb, 0, stream>>>(Wv, 0, WqkvTh + 2 * 1024 * 1024, WqkvTl + 2 * 1024 * 1024, 0, 1024, 1024);
  transpose_split_k<true><<<dim3(8, 32, 1), tb, 0, stream>>>(Wo, 0, WoTh, WoTl, 0, 1024, 1024);
  catb_k<<<12, 256, 0, stream>>>(bq, bk, bv, bqkv);

  // Phase 1: fused QKV projection (bf16x3) -> qkv hi/lo [2048][3072], cols rho'd
  {
    GemmArgs g{};
    g.Ah = srcH; g.Al = srcL; g.lda = 1024;
    g.Bh = WqkvTh; g.Bl = WqkvTl; g.ldb = 1024;
    g.Ch = qkvH; g.Cl = qkvL; g.ldc = 3072;
    g.bias = bqkv; g.K = 1024; g.Z2 = 0;
    g.NX = 16; g.NY = 32; g.YG = 8;
    gemm_k<128, 96, true, 1, true, 2, true><<<dim3(512), 256, 0, stream>>>(g);
  }
  // v slice -> vT [b][d][t] hi/lo (lossless re-layout, t rho'd)
  transpose_pair_k<<<dim3(32, 16, 4), tb, 0, stream>>>(qkvH, qkvL, vTH, vTL);

  // Phase 2: scores = q @ k^T (bf16x3), batched over (b,h), t-cols rho'd
  {
    GemmArgs g{};
    g.Ah = qkvH; g.Al = qkvL; g.lda = 3072;
    g.Bh = qkvH + 1024; g.Bl = qkvL + 1024; g.ldb = 3072;
    g.C = scores; g.ldc = 512;
    g.K = 64; g.Z2 = 16;
    g.aZ1 = 512ll * 3072; g.aZ2 = 64;
    g.bZ1 = 512ll * 3072; g.bZ2 = 64;
    g.cZ1 = 16ll * 512 * 512; g.cZ2 = 512ll * 512;
    gemm_k<128, 64, true, 0, true, 3, false><<<dim3(4, 8, 64), 256, 0, stream>>>(g);
  }
  softmax_k<<<64 * 512, 128, 0, stream>>>(scores);
  // PV: attn = probs @ v (bf16x3) -> attn hi/lo, d-cols rho'd
  {
    GemmArgs g{};
    g.Ah = (const u16*)scores; g.Al = (const u16*)scores + 512; g.lda = 1024;
    g.Bh = vTH; g.Bl = vTL; g.ldb = 512;
    g.Ch = attnH; g.Cl = attnL; g.ldc = 1024;
    g.K = 512; g.Z2 = 16;
    g.aZ1 = 16ll * 512 * 1024; g.aZ2 = 512ll * 1024;
    g.bZ1 = 1024ll * 512;      g.bZ2 = 64ll * 512;
    g.cZ1 = 512ll * 1024;      g.cZ2 = 64;
    gemm_k<64, 64, true, 1, true, 3, false><<<dim3(8, 1, 64), 256, 0, stream>>>(g);
  }
  // Wo projection (bf16x3) + bias -> plain f32 (feeds LN/residual)
  {
    GemmArgs g{};
    g.Ah = attnH; g.Al = attnL; g.lda = 1024;
    g.Bh = WoTh; g.Bl = WoTl; g.ldb = 1024;
    g.C = woOut; g.ldc = 1024;
    g.bias = bo; g.K = 1024; g.Z2 = 0;
    gemm_k<64, 64, true, 0, false, 3, false><<<dim3(32, 16, 1), 256, 0, stream>>>(g);
  }
  // ln1 + fused router
  ln_router_k<<<2048, 256, 0, stream>>>(src, woOut, g1, be1, rw, rb, xbuf, eidx);

  // Phase 3: routing
  compact_k<<<1, 256, 0, stream>>>(eidx, rowsrc, ofs);
  gather_k<<<2560, 256, 0, stream>>>(xbuf, rowsrc, ofs, xg);

  // FFN weights -> bf16 transposed (into dead scores region), k-dims rho'd
  transpose_split_k<false><<<dim3(32, 32, 4), tb, 0, stream>>>(W1, 1024ll * 4096, W1T, nullptr, 4096ll * 1024, 1024, 4096);
  transpose_split_k<false><<<dim3(8, 128, 4), tb, 0, stream>>>(W2, 4096ll * 1024, W2T, nullptr, 1024ll * 4096, 4096, 1024);

  // FFN1: h = relu(xg @ W1[e] + b1[e]) -> bf16, cols rho'd
  {
    GemmArgs g{};
    g.Ah = xg; g.lda = 1024;
    g.Bh = W1T; g.ldb = 1024;
    g.Ch = hbuf; g.ldc = 4096;
    g.bias = b1; g.biasStrE = 4096;
    g.K = 1024; g.Z2 = 0;
    g.ofs = ofs; g.bStrE = 4096ll * 1024;
    g.NX = 20; g.NY = 32; g.YG = 16;
    gemm_k<128, 128, false, 2, true, 3, true><<<dim3(640), 256, 0, stream>>>(g);
  }
  // FFN2 split-K x2: partial[c] = h[:, c*2048:(c+1)*2048] @ W2[e][c*2048:..., :]
  {
    GemmArgs g{};
    g.Ah = hbuf; g.lda = 4096;
    g.Bh = W2T; g.ldb = 4096;
    g.C = partials; g.ldc = 1024;
    g.bias = nullptr;
    g.K = 2048; g.Z2 = 2;
    g.aZ1 = 0; g.aZ2 = 2048;       // K-chunk offset within A row
    g.bZ1 = 0; g.bZ2 = 2048;       // K-chunk offset within B row
    g.cZ1 = 0; g.cZ2 = 2560ll * 1024;
    g.ofs = ofs; g.bStrE = 4096ll * 1024;
    g.NX = 20; g.NY = 16; g.YG = 16;
    gemm_k<128, 64, false, 0, false, 3, true><<<dim3(640), 256, 0, stream>>>(g);
  }
  // fused: reduce split-K + b2 + residual + LN2 + scatter to out
  reduce_ln_k<<<2560, 256, 0, stream>>>(partials, rowsrc, ofs, b2, xbuf, g2, be2, out);
}